// Round 5
// baseline (265.115 us; speedup 1.0000x reference)
//
#include <hip/hip_runtime.h>
#include <math.h>

#define HD 16      // hidden dim
#define NC 4       // num classes
#define BSH 8      // log2(nodes per fine bucket)
#define BSZ 256    // nodes per fine bucket
#define NSB 64     // super-buckets (64 * 4096 = 262144 >= N)
#define SBSH 12    // log2(nodes per super-bucket)
#define CAP1 69632 // per-super-bucket capacity (mean 65536 + 16 sigma)
#define CAP2 5120  // per-fine-bucket capacity (mean 4096 + 16 sigma)
#define NFB 1024   // fine buckets total (NSB * 16)
#define P2T 512    // threads in part2
#define NIV 17     // intervals = HD + 1
#define STR 35     // LDS P/Q row stride per node (odd -> conflict-free)
#define SMASK 0x3FFFFu  // low 18 bits = src id

// ---------- tiny prep: sorted relu thresholds + per-feature split/sign ----------
__global__ void k_thr(const float* __restrict__ W1, const float* __restrict__ b1,
                      float* __restrict__ ts, int* __restrict__ splits,
                      int* __restrict__ signs) {
    if (threadIdx.x != 0 || blockIdx.x != 0) return;
    float t[HD], s[HD];
    for (int f = 0; f < HD; ++f) {
        float w = W1[f];
        t[f] = (w != 0.0f) ? (-b1[f] / w) : INFINITY;
        s[f] = t[f];
    }
    for (int i = 1; i < HD; ++i) {            // insertion sort
        float key = s[i]; int j = i - 1;
        while (j >= 0 && s[j] > key) { s[j + 1] = s[j]; --j; }
        s[j + 1] = key;
    }
    for (int f = 0; f < HD; ++f) ts[f] = s[f];
    for (int f = 0; f < HD; ++f) {
        float w = W1[f];
        if (w == 0.0f) { signs[f] = 0; splits[f] = 0; continue; }
        int c = 0;
        for (int g = 0; g < HD; ++g) c += (s[g] < t[f]) ? 1 : 0;
        splits[f] = c + 1;                    // prefix index
        signs[f] = (w > 0.0f) ? 1 : -1;
    }
}

// ---------- pass 1: partition edges into 64 super-buckets ----------
// G1=1024 (R4 lesson: 2048 blocks doubled cursor contention + halved write runs).
__global__ void k_part1(const int* __restrict__ row, const int* __restrict__ col,
                        int* __restrict__ cursor1, unsigned* __restrict__ bins1,
                        int E, int CHK) {
    __shared__ int hist4[4][NSB + 1];
    __shared__ int lbase[NSB];
    __shared__ int ofs[NSB];
    int t = threadIdx.x;
    int cb = blockIdx.x * CHK;
    int ce = min(E, cb + CHK);
    if (cb >= ce) return;
    int n = ce - cb;
    int nv = n >> 2;                       // uint4 groups (cb is 4-aligned)
    const uint4* col4 = reinterpret_cast<const uint4*>(col + cb);
    const uint4* row4 = reinterpret_cast<const uint4*>(row + cb);
    int cp = (t >> 4) & 3;
    if (t < NSB) { hist4[0][t] = 0; hist4[1][t] = 0; hist4[2][t] = 0; hist4[3][t] = 0; }
    __syncthreads();
    for (int i = t; i < nv; i += 256) {
        uint4 c4 = col4[i];
        atomicAdd(&hist4[cp][c4.x >> SBSH], 1);
        atomicAdd(&hist4[cp][c4.y >> SBSH], 1);
        atomicAdd(&hist4[cp][c4.z >> SBSH], 1);
        atomicAdd(&hist4[cp][c4.w >> SBSH], 1);
    }
    for (int e = cb + (nv << 2) + t; e < ce; e += 256)
        atomicAdd(&hist4[cp][(unsigned)col[e] >> SBSH], 1);
    __syncthreads();
    if (t < NSB) {
        int h = hist4[0][t] + hist4[1][t] + hist4[2][t] + hist4[3][t];
        lbase[t] = h ? atomicAdd(&cursor1[t * 16], h) : 0;
        ofs[t] = 0;
    }
    __syncthreads();
    for (int i = t; i < nv; i += 256) {
        uint4 c4 = col4[i];
        uint4 r4 = row4[i];
        {
            int sb = (int)(c4.x >> SBSH);
            int pos = lbase[sb] + atomicAdd(&ofs[sb], 1);
            if (pos < CAP1)
                bins1[(size_t)sb * CAP1 + pos] = r4.x | ((c4.x & 4095u) << 18);
        }
        {
            int sb = (int)(c4.y >> SBSH);
            int pos = lbase[sb] + atomicAdd(&ofs[sb], 1);
            if (pos < CAP1)
                bins1[(size_t)sb * CAP1 + pos] = r4.y | ((c4.y & 4095u) << 18);
        }
        {
            int sb = (int)(c4.z >> SBSH);
            int pos = lbase[sb] + atomicAdd(&ofs[sb], 1);
            if (pos < CAP1)
                bins1[(size_t)sb * CAP1 + pos] = r4.z | ((c4.z & 4095u) << 18);
        }
        {
            int sb = (int)(c4.w >> SBSH);
            int pos = lbase[sb] + atomicAdd(&ofs[sb], 1);
            if (pos < CAP1)
                bins1[(size_t)sb * CAP1 + pos] = r4.w | ((c4.w & 4095u) << 18);
        }
    }
    for (int e = cb + (nv << 2) + t; e < ce; e += 256) {
        unsigned c = (unsigned)col[e];
        int sb = (int)(c >> SBSH);
        int pos = lbase[sb] + atomicAdd(&ofs[sb], 1);
        if (pos < CAP1)
            bins1[(size_t)sb * CAP1 + pos] = (unsigned)row[e] | ((c & 4095u) << 18);
    }
}

// ---------- pass 2 (owner-gather): one block OWNS one fine bucket ----------
// Scans its whole super-bucket (L2-resident; XCD-swizzled so the 16 sibling
// blocks share one L2 copy), compacts matches via wave-ballot (1 LDS atomic
// per wave, contiguous writes), counts degrees in LDS, and emits dinv/dx.
// Replaces scatter-part2 AND k_degdx. No global cursor atomics.
__global__ void k_part2(const unsigned* __restrict__ bins1, const int* __restrict__ cursor1,
                        int* __restrict__ cursor2, unsigned* __restrict__ bins2,
                        const float* __restrict__ x,
                        float* __restrict__ dinv, float* __restrict__ dx, int N) {
    __shared__ int cnt[BSZ];   // per-node degree counters
    __shared__ int wcnt;       // bucket write cursor
    int t = threadIdx.x;
    int g = blockIdx.x;
    // XCD swizzle: all 16 blocks of a super-bucket get the same (g & 7)
    int sb = (g & 7) | ((g >> 7) << 3);
    int fl = (g >> 3) & 15;
    int fb = sb * 16 + fl;
    if (t < BSZ) cnt[t] = 0;
    if (t == 0) wcnt = 0;
    __syncthreads();
    int cnt1 = cursor1[sb * 16];
    if (cnt1 > CAP1) cnt1 = CAP1;
    const unsigned* ibase = bins1 + (size_t)sb * CAP1;
    unsigned* obase = bins2 + (size_t)fb * CAP2;
    int lane = t & 63;
    unsigned long long lmask = (lane == 63) ? ~0ull >> 1 : (1ull << lane) - 1;
    lmask = (1ull << lane) - 1;  // lane<64, shift safe on 64-bit
    int nv = cnt1 >> 2;
    const uint4* b4 = reinterpret_cast<const uint4*>(ibase);
    for (int i = t; i < nv; i += P2T) {
        uint4 rr = b4[i];
        #pragma unroll
        for (int q = 0; q < 4; ++q) {
            unsigned rec = (q == 0) ? rr.x : (q == 1) ? rr.y : (q == 2) ? rr.z : rr.w;
            bool mt = ((rec >> 26) == (unsigned)fl);
            unsigned long long msk = __ballot(mt);
            if (msk) {
                int ldr = __ffsll((unsigned long long)msk) - 1;
                int base = 0;
                if (lane == ldr) base = atomicAdd(&wcnt, __popcll(msk));
                base = __shfl(base, ldr);
                if (mt) {
                    int pos = base + __popcll(msk & lmask);
                    unsigned nb = (rec >> 18) & 255u;
                    if (pos < CAP2) obase[pos] = (rec & SMASK) | (nb << 18);
                    atomicAdd(&cnt[nb], 1);
                }
            }
        }
    }
    for (int j = (nv << 2) + t; j < cnt1; j += P2T) {
        unsigned rec = ibase[j];
        bool mt = ((rec >> 26) == (unsigned)fl);
        unsigned long long msk = __ballot(mt);
        if (msk) {
            int ldr = __ffsll((unsigned long long)msk) - 1;
            int base = 0;
            if (lane == ldr) base = atomicAdd(&wcnt, __popcll(msk));
            base = __shfl(base, ldr);
            if (mt) {
                int pos = base + __popcll(msk & lmask);
                unsigned nb = (rec >> 18) & 255u;
                if (pos < CAP2) obase[pos] = (rec & SMASK) | (nb << 18);
                atomicAdd(&cnt[nb], 1);
            }
        }
    }
    __syncthreads();
    if (t == 0) cursor2[fb * 16] = wcnt;
    int node = (fb << BSH) + t;
    if (t < BSZ && node < N) {
        float d = rsqrtf((float)(cnt[t] + 1));
        dinv[node] = d;
        dx[node] = d * x[node];
    }
}

// ---------- layer-1 scalar aggregate (per fine bucket) ----------
// epilogue classifies each node's S into its relu interval k and packs k
// into the low 5 mantissa bits of dinv (error ~2e-6 rel, tolerance 1e-3)
__global__ void k_s1(const unsigned* __restrict__ bins, const int* __restrict__ cursor,
                     const float* __restrict__ dinv, const float* __restrict__ dx,
                     const float* __restrict__ ts,
                     float2* __restrict__ gpq, int N) {
    __shared__ float sacc[BSZ];
    int t = threadIdx.x, b = blockIdx.x;
    sacc[t] = 0.0f;
    __syncthreads();
    int m = cursor[b * 16];
    if (m > CAP2) m = CAP2;
    int s = b * CAP2, e = s + m;
    int full = ((e - s) >> 10) << 10;
    int ev = s + full;
    for (int j = s + (t << 2); j < ev; j += 1024) {
        uint4 rr = *reinterpret_cast<const uint4*>(bins + j);
        float v0 = dx[rr.x & SMASK], v1 = dx[rr.y & SMASK],
              v2 = dx[rr.z & SMASK], v3 = dx[rr.w & SMASK];
        atomicAdd(&sacc[rr.x >> 18], v0);
        atomicAdd(&sacc[rr.y >> 18], v1);
        atomicAdd(&sacc[rr.z >> 18], v2);
        atomicAdd(&sacc[rr.w >> 18], v3);
    }
    for (int j = ev + t; j < e; j += 256) {
        unsigned r = bins[j];
        atomicAdd(&sacc[r >> 18], dx[r & SMASK]);
    }
    __syncthreads();
    int node = (b << BSH) + t;
    if (node < N) {
        float d = dinv[node];
        float S = d * (sacc[t] + dx[node]);   // + self-loop dinv^2*x
        int k = 0;
        #pragma unroll
        for (int g = 0; g < HD; ++g) k += (S > ts[g]);
        unsigned dq = (__float_as_uint(d) & ~31u) | (unsigned)k;
        gpq[node] = make_float2(d * S, __uint_as_float(dq));
    }
}

// ---------- layer-2: interval-bucketed LDS aggregate + fused recon/epilogue ----------
__global__ void __launch_bounds__(256, 1)
k_agg(const unsigned* __restrict__ bins, const int* __restrict__ cursor,
      const float2* __restrict__ gpq, const float* __restrict__ dinv,
      const int* __restrict__ splits, const int* __restrict__ signs,
      const float* __restrict__ W1, const float* __restrict__ b1,
      const float* __restrict__ W2, const float* __restrict__ b2,
      const float* __restrict__ Wfc, const float* __restrict__ bfc,
      float* __restrict__ out, int N) {
    __shared__ float acc[BSZ * STR];   // 35.8 KB
    int t = threadIdx.x, b = blockIdx.x;
    for (int i = t; i < BSZ * STR; i += 256) acc[i] = 0.0f;
    __syncthreads();

    int m = cursor[b * 16];
    if (m > CAP2) m = CAP2;
    int s = b * CAP2, e = s + m;
    int full = ((e - s) >> 10) << 10;
    int ev = s + full;
    for (int j = s + (t << 2); j < ev; j += 1024) {
        uint4 rr = *reinterpret_cast<const uint4*>(bins + j);
        float2 p0 = gpq[rr.x & SMASK], p1 = gpq[rr.y & SMASK],
               p2 = gpq[rr.z & SMASK], p3 = gpq[rr.w & SMASK];
        float* a0 = &acc[(int)(rr.x >> 18) * STR + 2 * (int)(__float_as_uint(p0.y) & 31u)];
        float* a1 = &acc[(int)(rr.y >> 18) * STR + 2 * (int)(__float_as_uint(p1.y) & 31u)];
        float* a2 = &acc[(int)(rr.z >> 18) * STR + 2 * (int)(__float_as_uint(p2.y) & 31u)];
        float* a3 = &acc[(int)(rr.w >> 18) * STR + 2 * (int)(__float_as_uint(p3.y) & 31u)];
        atomicAdd(a0, p0.x); atomicAdd(a0 + 1, p0.y);
        atomicAdd(a1, p1.x); atomicAdd(a1 + 1, p1.y);
        atomicAdd(a2, p2.x); atomicAdd(a2 + 1, p2.y);
        atomicAdd(a3, p3.x); atomicAdd(a3 + 1, p3.y);
    }
    for (int j = ev + t; j < e; j += 256) {
        unsigned r = bins[j];
        float2 p = gpq[r & SMASK];
        float* a = &acc[(int)(r >> 18) * STR + 2 * (int)(__float_as_uint(p.y) & 31u)];
        atomicAdd(a, p.x); atomicAdd(a + 1, p.y);
    }
    __syncthreads();

    // ---- reconstruction + epilogue ----
    int node = (b << BSH) + t;
    if (node >= N) return;
    float Ppre[NIV + 1], Qpre[NIV + 1];
    float pp = 0.0f, qq = 0.0f;
    #pragma unroll
    for (int mm = 0; mm < NIV; ++mm) {
        Ppre[mm] = pp; Qpre[mm] = qq;
        pp += acc[t * STR + 2 * mm];
        qq += acc[t * STR + 2 * mm + 1];
    }
    Ppre[NIV] = pp; Qpre[NIV] = qq;

    float2 pq = gpq[node];
    float di = dinv[node];        // exact dinv (gpq.y carries packed k bits)
    float si = pq.x / di;         // S = (d*S)/d
    float aggv[HD];
    #pragma unroll
    for (int f = 0; f < HD; ++f) {
        int sp = splits[f], sg = signs[f];
        float w = W1[f], bb = b1[f];
        float A, B;
        if (sg > 0)      { A = pp - Ppre[sp]; B = qq - Qpre[sp]; }
        else if (sg < 0) { A = Ppre[sp];      B = Qpre[sp]; }
        else             { A = 0.0f;          B = (bb > 0.0f) ? qq : 0.0f; }
        float selfh = fmaxf(fmaf(w, si, bb), 0.0f);
        aggv[f] = di * (fmaf(w, A, bb * B) + di * selfh);
    }
    float o0 = bfc[0], o1 = bfc[1], o2 = bfc[2], o3 = bfc[3];
    #pragma unroll
    for (int f2 = 0; f2 < HD; ++f2) {
        float h = b2[f2];
        #pragma unroll
        for (int k = 0; k < HD; ++k) h = fmaf(aggv[k], W2[k * HD + f2], h);
        h = fmaxf(h, 0.0f);
        o0 = fmaf(h, Wfc[f2 * NC + 0], o0);
        o1 = fmaf(h, Wfc[f2 * NC + 1], o1);
        o2 = fmaf(h, Wfc[f2 * NC + 2], o2);
        o3 = fmaf(h, Wfc[f2 * NC + 3], o3);
    }
    ((float4*)out)[node] = make_float4(o0, o1, o2, o3);
}

extern "C" void kernel_launch(void* const* d_in, const int* in_sizes, int n_in,
                              void* d_out, int out_size, void* d_ws, size_t ws_size,
                              hipStream_t stream) {
    const float* x   = (const float*)d_in[0];
    const int*   ei  = (const int*)d_in[1];
    const float* W1  = (const float*)d_in[2];
    const float* b1  = (const float*)d_in[3];
    const float* W2  = (const float*)d_in[4];
    const float* b2  = (const float*)d_in[5];
    const float* Wfc = (const float*)d_in[6];
    const float* bfc = (const float*)d_in[7];
    float* out = (float*)d_out;

    const int N = in_sizes[0];            // 250000 (< 2^18)
    const int E = in_sizes[1] / 2;        // 4000000
    const int* row = ei;
    const int* col = ei + E;

    // workspace layout (~43 MB)
    char* ws = (char*)d_ws;
    size_t off = 0;
    unsigned* bins1 = (unsigned*)(ws + off); off += (size_t)NSB * CAP1 * 4;   // 17.8 MB
    unsigned* bins2 = (unsigned*)(ws + off); off += (size_t)NFB * CAP2 * 4;   // 21 MB
    int*    cursor1= (int*)(ws + off);   off += (size_t)NSB * 16 * 4;         // 4 KB
    int*    cursor2= (int*)(ws + off);   off += (size_t)NFB * 16 * 4;         // 64 KB
    float*  dinv  = (float*)(ws + off);  off += (size_t)N * 4;
    float*  dx    = (float*)(ws + off);  off += (size_t)N * 4;
    float2* gpq   = (float2*)(ws + off); off += (size_t)N * 8;                // (d*S, d|k)
    float*  ts    = (float*)(ws + off);  off += 64;
    int*    splits= (int*)(ws + off);    off += 64;
    int*    signs = (int*)(ws + off);    off += 64;

    hipMemsetAsync(cursor1, 0, (size_t)NSB * 16 * 4, stream);  // only cursor1 is atomic-accumulated

    const int B = 256;
    k_thr<<<1, 64, 0, stream>>>(W1, b1, ts, splits, signs);
    const int G1 = 1024;
    int CHK = (E + G1 - 1) / G1;
    CHK = (CHK + 3) & ~3;                 // keep uint4 alignment per chunk
    k_part1<<<G1, B, 0, stream>>>(row, col, cursor1, bins1, E, CHK);
    k_part2<<<NFB, P2T, 0, stream>>>(bins1, cursor1, cursor2, bins2, x, dinv, dx, N);
    k_s1<<<NFB, B, 0, stream>>>(bins2, cursor2, dinv, dx, ts, gpq, N);
    k_agg<<<NFB, B, 0, stream>>>(bins2, cursor2, gpq, dinv, splits, signs,
                                 W1, b1, W2, b2, Wfc, bfc, out, N);
}

// Round 7
// 234.900 us; speedup vs baseline: 1.1286x; 1.1286x over previous
//
#include <hip/hip_runtime.h>
#include <math.h>

#define HD 16      // hidden dim
#define NC 4       // num classes
#define BSH 8      // log2(nodes per fine bucket)
#define BSZ 256    // nodes per fine bucket
#define NSB 64     // super-buckets (64 * 4096 = 262144 >= N)
#define SBSH 12    // log2(nodes per super-bucket)
#define CAP1 69632 // per-super-bucket capacity (mean 65536 + 16 sigma)
#define CAP2 5120  // per-fine-bucket capacity (mean 4096 + 16 sigma)
#define S2 16      // splits per super-bucket in pass 2
#define NFB 1024   // fine buckets total (NSB * 16)
#define NIV 17     // intervals = HD + 1
#define STR 35     // LDS P/Q row stride per node (odd -> conflict-free)
#define AGT 512    // k_agg threads (4 blocks/CU x 512 = 2048 = 100% thread slots)
#define SMASK 0x3FFFFu  // low 18 bits = src id

// ---------- prep: zero cursors + sorted relu thresholds + split/sign ----------
// (memset folded in: threads zero the contiguous cursor1+cursor2 region)
__global__ void k_thr(const float* __restrict__ W1, const float* __restrict__ b1,
                      float* __restrict__ ts, int* __restrict__ splits,
                      int* __restrict__ signs, int* __restrict__ cursors, int ncur) {
    int t = threadIdx.x;
    for (int i = t; i < ncur; i += 256) cursors[i] = 0;
    if (t != 0) return;
    float tt[HD], s[HD];
    for (int f = 0; f < HD; ++f) {
        float w = W1[f];
        tt[f] = (w != 0.0f) ? (-b1[f] / w) : INFINITY;
        s[f] = tt[f];
    }
    for (int i = 1; i < HD; ++i) {            // insertion sort
        float key = s[i]; int j = i - 1;
        while (j >= 0 && s[j] > key) { s[j + 1] = s[j]; --j; }
        s[j + 1] = key;
    }
    for (int f = 0; f < HD; ++f) ts[f] = s[f];
    for (int f = 0; f < HD; ++f) {
        float w = W1[f];
        if (w == 0.0f) { signs[f] = 0; splits[f] = 0; continue; }
        int c = 0;
        for (int g = 0; g < HD; ++g) c += (s[g] < tt[f]) ? 1 : 0;
        splits[f] = c + 1;                    // prefix index
        signs[f] = (w > 0.0f) ? 1 : -1;
    }
}

// ---------- pass 1: partition edges into 64 super-buckets (R1-proven form) ----------
__global__ void k_part1(const int* __restrict__ row, const int* __restrict__ col,
                        int* __restrict__ cursor1, unsigned* __restrict__ bins1,
                        int E, int CHK) {
    __shared__ int hist[NSB];
    __shared__ int lbase[NSB];
    int t = threadIdx.x;
    int cb = blockIdx.x * CHK;
    int ce = min(E, cb + CHK);
    if (t < NSB) hist[t] = 0;
    __syncthreads();
    for (int e = cb + t; e < ce; e += blockDim.x)
        atomicAdd(&hist[col[e] >> SBSH], 1);
    __syncthreads();
    if (t < NSB) {
        int h = hist[t];
        lbase[t] = h ? atomicAdd(&cursor1[t * 16], h) : 0;
        hist[t] = 0;                           // reuse as offsets
    }
    __syncthreads();
    for (int e = cb + t; e < ce; e += blockDim.x) {
        int c = col[e];
        int sb = c >> SBSH;
        int pos = lbase[sb] + atomicAdd(&hist[sb], 1);
        if (pos < CAP1)
            bins1[(size_t)sb * CAP1 + pos] =
                (unsigned)row[e] | ((unsigned)(c & 4095) << 18);
    }
}

// ---------- pass 2: split each super-bucket into 16 fine buckets (R1-proven form) ----------
__global__ void k_part2(const unsigned* __restrict__ bins1, const int* __restrict__ cursor1,
                        int* __restrict__ cursor2, unsigned* __restrict__ bins2) {
    __shared__ int hist4[4][17];   // 4 wave-quarter copies, padded
    __shared__ int lbase[16];
    __shared__ int ofs[16];
    int t = threadIdx.x;
    int sb = blockIdx.x >> 4;
    int sp = blockIdx.x & 15;
    int cnt = cursor1[sb * 16];
    if (cnt > CAP1) cnt = CAP1;
    int s0 = sb * CAP1;
    int js = s0 + (int)(((long long)cnt * sp) / S2);
    int je = s0 + (int)(((long long)cnt * (sp + 1)) / S2);
    if (t < 16) { hist4[0][t] = 0; hist4[1][t] = 0; hist4[2][t] = 0; hist4[3][t] = 0; }
    __syncthreads();
    int cp = (t >> 4) & 3;
    for (int j = js + t; j < je; j += 256)
        atomicAdd(&hist4[cp][bins1[j] >> 26], 1);
    __syncthreads();
    if (t < 16) {
        int h = hist4[0][t] + hist4[1][t] + hist4[2][t] + hist4[3][t];
        lbase[t] = h ? atomicAdd(&cursor2[(sb * 16 + t) * 16], h) : 0;
        ofs[t] = 0;
    }
    __syncthreads();
    for (int j = js + t; j < je; j += 256) {
        unsigned rec = bins1[j];
        int fl = rec >> 26;
        int pos = lbase[fl] + atomicAdd(&ofs[fl], 1);
        if (pos < CAP2)
            bins2[(size_t)(sb * 16 + fl) * CAP2 + pos] =
                (rec & SMASK) | (((rec >> 18) & 255u) << 18);
    }
}

// ---------- fused degree + dinv + dx (per fine bucket) ----------
__global__ void k_degdx(const unsigned* __restrict__ bins, const int* __restrict__ cursor,
                        const float* __restrict__ x,
                        float* __restrict__ dinv, float* __restrict__ dx, int N) {
    __shared__ int cnt[BSZ];
    int t = threadIdx.x, b = blockIdx.x;
    cnt[t] = 0;
    __syncthreads();
    int m = cursor[b * 16];
    if (m > CAP2) m = CAP2;
    int s = b * CAP2, e = s + m;
    int full = ((e - s) >> 10) << 10;
    int ev = s + full;
    for (int j = s + (t << 2); j < ev; j += 1024) {
        uint4 rr = *reinterpret_cast<const uint4*>(bins + j);
        atomicAdd(&cnt[rr.x >> 18], 1);
        atomicAdd(&cnt[rr.y >> 18], 1);
        atomicAdd(&cnt[rr.z >> 18], 1);
        atomicAdd(&cnt[rr.w >> 18], 1);
    }
    for (int j = ev + t; j < e; j += 256) atomicAdd(&cnt[bins[j] >> 18], 1);
    __syncthreads();
    int node = (b << BSH) + t;
    if (node < N) {
        float d = rsqrtf((float)(cnt[t] + 1));
        dinv[node] = d;
        dx[node] = d * x[node];
    }
}

// ---------- layer-1 scalar aggregate (per fine bucket) ----------
// epilogue classifies each node's S into its relu interval k and packs k
// into the low 5 mantissa bits of dinv (error ~2e-6 rel, tolerance 1e-3)
__global__ void k_s1(const unsigned* __restrict__ bins, const int* __restrict__ cursor,
                     const float* __restrict__ dinv, const float* __restrict__ dx,
                     const float* __restrict__ ts,
                     float2* __restrict__ gpq, int N) {
    __shared__ float sacc[BSZ];
    int t = threadIdx.x, b = blockIdx.x;
    sacc[t] = 0.0f;
    __syncthreads();
    int m = cursor[b * 16];
    if (m > CAP2) m = CAP2;
    int s = b * CAP2, e = s + m;
    int full = ((e - s) >> 10) << 10;
    int ev = s + full;
    for (int j = s + (t << 2); j < ev; j += 1024) {
        uint4 rr = *reinterpret_cast<const uint4*>(bins + j);
        float v0 = dx[rr.x & SMASK], v1 = dx[rr.y & SMASK],
              v2 = dx[rr.z & SMASK], v3 = dx[rr.w & SMASK];
        atomicAdd(&sacc[rr.x >> 18], v0);
        atomicAdd(&sacc[rr.y >> 18], v1);
        atomicAdd(&sacc[rr.z >> 18], v2);
        atomicAdd(&sacc[rr.w >> 18], v3);
    }
    for (int j = ev + t; j < e; j += 256) {
        unsigned r = bins[j];
        atomicAdd(&sacc[r >> 18], dx[r & SMASK]);
    }
    __syncthreads();
    int node = (b << BSH) + t;
    if (node < N) {
        float d = dinv[node];
        float S = d * (sacc[t] + dx[node]);   // + self-loop dinv^2*x
        int k = 0;
        #pragma unroll
        for (int g = 0; g < HD; ++g) k += (S > ts[g]);
        unsigned dq = (__float_as_uint(d) & ~31u) | (unsigned)k;
        gpq[node] = make_float2(d * S, __uint_as_float(dq));
    }
}

// ---------- layer-2: interval-bucketed LDS aggregate + fused recon/epilogue ----------
// 512 threads, same 35.8 KB LDS: 4 blocks/CU x 8 waves = 32 waves/CU (was 16)
__global__ void __launch_bounds__(AGT, 1)
k_agg(const unsigned* __restrict__ bins, const int* __restrict__ cursor,
      const float2* __restrict__ gpq, const float* __restrict__ dinv,
      const int* __restrict__ splits, const int* __restrict__ signs,
      const float* __restrict__ W1, const float* __restrict__ b1,
      const float* __restrict__ W2, const float* __restrict__ b2,
      const float* __restrict__ Wfc, const float* __restrict__ bfc,
      float* __restrict__ out, int N) {
    __shared__ float acc[BSZ * STR];   // 35.8 KB
    int t = threadIdx.x, b = blockIdx.x;
    for (int i = t; i < BSZ * STR; i += AGT) acc[i] = 0.0f;
    __syncthreads();

    int m = cursor[b * 16];
    if (m > CAP2) m = CAP2;
    int s = b * CAP2, e = s + m;
    int nv = m >> 2;                       // full uint4 groups (s is 16B-aligned)
    const uint4* b4 = reinterpret_cast<const uint4*>(bins + s);
    for (int i = t; i < nv; i += AGT) {
        uint4 rr = b4[i];
        float2 p0 = gpq[rr.x & SMASK], p1 = gpq[rr.y & SMASK],
               p2 = gpq[rr.z & SMASK], p3 = gpq[rr.w & SMASK];
        float* a0 = &acc[(int)(rr.x >> 18) * STR + 2 * (int)(__float_as_uint(p0.y) & 31u)];
        float* a1 = &acc[(int)(rr.y >> 18) * STR + 2 * (int)(__float_as_uint(p1.y) & 31u)];
        float* a2 = &acc[(int)(rr.z >> 18) * STR + 2 * (int)(__float_as_uint(p2.y) & 31u)];
        float* a3 = &acc[(int)(rr.w >> 18) * STR + 2 * (int)(__float_as_uint(p3.y) & 31u)];
        atomicAdd(a0, p0.x); atomicAdd(a0 + 1, p0.y);
        atomicAdd(a1, p1.x); atomicAdd(a1 + 1, p1.y);
        atomicAdd(a2, p2.x); atomicAdd(a2 + 1, p2.y);
        atomicAdd(a3, p3.x); atomicAdd(a3 + 1, p3.y);
    }
    for (int j = s + (nv << 2) + t; j < e; j += AGT) {
        unsigned r = bins[j];
        float2 p = gpq[r & SMASK];
        float* a = &acc[(int)(r >> 18) * STR + 2 * (int)(__float_as_uint(p.y) & 31u)];
        atomicAdd(a, p.x); atomicAdd(a + 1, p.y);
    }
    __syncthreads();

    // ---- reconstruction + epilogue (first 256 lanes; one node each) ----
    int node = (b << BSH) + t;
    if (t >= BSZ || node >= N) return;
    float Ppre[NIV + 1], Qpre[NIV + 1];
    float pp = 0.0f, qq = 0.0f;
    #pragma unroll
    for (int mm = 0; mm < NIV; ++mm) {
        Ppre[mm] = pp; Qpre[mm] = qq;
        pp += acc[t * STR + 2 * mm];
        qq += acc[t * STR + 2 * mm + 1];
    }
    Ppre[NIV] = pp; Qpre[NIV] = qq;

    float2 pq = gpq[node];
    float di = dinv[node];        // exact dinv (gpq.y carries packed k bits)
    float si = pq.x / di;         // S = (d*S)/d
    float aggv[HD];
    #pragma unroll
    for (int f = 0; f < HD; ++f) {
        int sp = splits[f], sg = signs[f];
        float w = W1[f], bb = b1[f];
        float A, B;
        if (sg > 0)      { A = pp - Ppre[sp]; B = qq - Qpre[sp]; }
        else if (sg < 0) { A = Ppre[sp];      B = Qpre[sp]; }
        else             { A = 0.0f;          B = (bb > 0.0f) ? qq : 0.0f; }
        float selfh = fmaxf(fmaf(w, si, bb), 0.0f);
        aggv[f] = di * (fmaf(w, A, bb * B) + di * selfh);
    }
    float o0 = bfc[0], o1 = bfc[1], o2 = bfc[2], o3 = bfc[3];
    #pragma unroll
    for (int f2 = 0; f2 < HD; ++f2) {
        float h = b2[f2];
        #pragma unroll
        for (int k = 0; k < HD; ++k) h = fmaf(aggv[k], W2[k * HD + f2], h);
        h = fmaxf(h, 0.0f);
        o0 = fmaf(h, Wfc[f2 * NC + 0], o0);
        o1 = fmaf(h, Wfc[f2 * NC + 1], o1);
        o2 = fmaf(h, Wfc[f2 * NC + 2], o2);
        o3 = fmaf(h, Wfc[f2 * NC + 3], o3);
    }
    ((float4*)out)[node] = make_float4(o0, o1, o2, o3);
}

extern "C" void kernel_launch(void* const* d_in, const int* in_sizes, int n_in,
                              void* d_out, int out_size, void* d_ws, size_t ws_size,
                              hipStream_t stream) {
    const float* x   = (const float*)d_in[0];
    const int*   ei  = (const int*)d_in[1];
    const float* W1  = (const float*)d_in[2];
    const float* b1  = (const float*)d_in[3];
    const float* W2  = (const float*)d_in[4];
    const float* b2  = (const float*)d_in[5];
    const float* Wfc = (const float*)d_in[6];
    const float* bfc = (const float*)d_in[7];
    float* out = (float*)d_out;

    const int N = in_sizes[0];            // 250000 (< 2^18)
    const int E = in_sizes[1] / 2;        // 4000000
    const int* row = ei;
    const int* col = ei + E;

    // workspace layout (~43 MB)
    char* ws = (char*)d_ws;
    size_t off = 0;
    unsigned* bins1 = (unsigned*)(ws + off); off += (size_t)NSB * CAP1 * 4;   // 17.8 MB
    unsigned* bins2 = (unsigned*)(ws + off); off += (size_t)NFB * CAP2 * 4;   // 21 MB
    int*    cursor1= (int*)(ws + off);   off += (size_t)NSB * 16 * 4;         // 4 KB   } contiguous,
    int*    cursor2= (int*)(ws + off);   off += (size_t)NFB * 16 * 4;         // 64 KB  } zeroed in k_thr
    float*  dinv  = (float*)(ws + off);  off += (size_t)N * 4;
    float*  dx    = (float*)(ws + off);  off += (size_t)N * 4;
    float2* gpq   = (float2*)(ws + off); off += (size_t)N * 8;                // (d*S, d|k)
    float*  ts    = (float*)(ws + off);  off += 64;
    int*    splits= (int*)(ws + off);    off += 64;
    int*    signs = (int*)(ws + off);    off += 64;

    const int B = 256;
    k_thr<<<1, B, 0, stream>>>(W1, b1, ts, splits, signs,
                               cursor1, (NSB + NFB) * 16);
    const int G1 = 1024;
    const int CHK = (E + G1 - 1) / G1;
    k_part1<<<G1, B, 0, stream>>>(row, col, cursor1, bins1, E, CHK);
    k_part2<<<NSB * S2, B, 0, stream>>>(bins1, cursor1, cursor2, bins2);
    k_degdx<<<NFB, B, 0, stream>>>(bins2, cursor2, x, dinv, dx, N);
    k_s1<<<NFB, B, 0, stream>>>(bins2, cursor2, dinv, dx, ts, gpq, N);
    k_agg<<<NFB, AGT, 0, stream>>>(bins2, cursor2, gpq, dinv, splits, signs,
                                   W1, b1, W2, b2, Wfc, bfc, out, N);
}

// Round 8
// 229.669 us; speedup vs baseline: 1.1543x; 1.0228x over previous
//
#include <hip/hip_runtime.h>
#include <math.h>

#define HD 16      // hidden dim
#define NC 4       // num classes
#define BSH 8      // log2(nodes per fine bucket)
#define BSZ 256    // nodes per fine bucket
#define NSB 64     // super-buckets (64 * 4096 = 262144 >= N)
#define SBSH 12    // log2(nodes per super-bucket)
#define CAP1 69632 // per-super-bucket capacity (mean 65536 + 16 sigma)
#define CAP2 5120  // per-fine-bucket capacity (mean 4096 + 16 sigma)
#define S2 16      // splits per super-bucket in pass 2
#define NFB 1024   // fine buckets total (NSB * 16)
#define NIV 17     // intervals = HD + 1
#define STR 35     // LDS P/Q row stride per node (odd -> conflict-free)
#define AGT 512    // k_agg threads (4 blocks/CU x 512 = 2048 = 100% thread slots)
#define CHKMAX 4096 // max edges per part1 block (CHK=3908 fits)
#define SMASK 0x3FFFFu  // low 18 bits = src id

// ---------- prep: zero cursors + sorted relu thresholds + split/sign ----------
__global__ void k_thr(const float* __restrict__ W1, const float* __restrict__ b1,
                      float* __restrict__ ts, int* __restrict__ splits,
                      int* __restrict__ signs, int* __restrict__ cursors, int ncur) {
    int t = threadIdx.x;
    for (int i = t; i < ncur; i += 256) cursors[i] = 0;
    if (t != 0) return;
    float tt[HD], s[HD];
    for (int f = 0; f < HD; ++f) {
        float w = W1[f];
        tt[f] = (w != 0.0f) ? (-b1[f] / w) : INFINITY;
        s[f] = tt[f];
    }
    for (int i = 1; i < HD; ++i) {            // insertion sort
        float key = s[i]; int j = i - 1;
        while (j >= 0 && s[j] > key) { s[j + 1] = s[j]; --j; }
        s[j + 1] = key;
    }
    for (int f = 0; f < HD; ++f) ts[f] = s[f];
    for (int f = 0; f < HD; ++f) {
        float w = W1[f];
        if (w == 0.0f) { signs[f] = 0; splits[f] = 0; continue; }
        int c = 0;
        for (int g = 0; g < HD; ++g) c += (s[g] < tt[f]) ? 1 : 0;
        splits[f] = c + 1;                    // prefix index
        signs[f] = (w > 0.0f) ? 1 : -1;
    }
}

// ---------- pass 1: partition edges into 64 super-buckets ----------
// col chunk staged in LDS during phase 1 (16 KB); phase 2 reads it back via
// ds_read_b128 instead of a second 16 MB global pass. uint4 loads, 4-copy hist.
// G1=1024 (R4 lesson: 2048 halves write runs + doubles cursor contention).
__global__ void k_part1(const int* __restrict__ row, const int* __restrict__ col,
                        int* __restrict__ cursor1, unsigned* __restrict__ bins1,
                        int E, int CHK) {
    __shared__ int hist4[4][NSB + 1];
    __shared__ int lbase[NSB];
    __shared__ int ofs[NSB];
    __shared__ unsigned cstage[CHKMAX];   // 16 KB col stage
    int t = threadIdx.x;
    int cb = blockIdx.x * CHK;
    int ce = min(E, cb + CHK);
    if (cb >= ce) return;
    int n = ce - cb;
    int nv = n >> 2;                       // uint4 groups (cb is 4-aligned)
    const uint4* col4 = reinterpret_cast<const uint4*>(col + cb);
    const uint4* row4 = reinterpret_cast<const uint4*>(row + cb);
    int cp = (t >> 4) & 3;
    if (t < NSB) { hist4[0][t] = 0; hist4[1][t] = 0; hist4[2][t] = 0; hist4[3][t] = 0; }
    __syncthreads();
    for (int i = t; i < nv; i += 256) {
        uint4 c4 = col4[i];
        reinterpret_cast<uint4*>(cstage)[i] = c4;
        atomicAdd(&hist4[cp][c4.x >> SBSH], 1);
        atomicAdd(&hist4[cp][c4.y >> SBSH], 1);
        atomicAdd(&hist4[cp][c4.z >> SBSH], 1);
        atomicAdd(&hist4[cp][c4.w >> SBSH], 1);
    }
    for (int e = (nv << 2) + t; e < n; e += 256) {
        unsigned c = (unsigned)col[cb + e];
        cstage[e] = c;
        atomicAdd(&hist4[cp][c >> SBSH], 1);
    }
    __syncthreads();
    if (t < NSB) {
        int h = hist4[0][t] + hist4[1][t] + hist4[2][t] + hist4[3][t];
        lbase[t] = h ? atomicAdd(&cursor1[t * 16], h) : 0;
        ofs[t] = 0;
    }
    __syncthreads();
    for (int i = t; i < nv; i += 256) {
        uint4 r4 = row4[i];
        uint4 c4 = reinterpret_cast<const uint4*>(cstage)[i];   // LDS, b128
        {
            int sb = (int)(c4.x >> SBSH);
            int pos = lbase[sb] + atomicAdd(&ofs[sb], 1);
            if (pos < CAP1)
                bins1[(size_t)sb * CAP1 + pos] = r4.x | ((c4.x & 4095u) << 18);
        }
        {
            int sb = (int)(c4.y >> SBSH);
            int pos = lbase[sb] + atomicAdd(&ofs[sb], 1);
            if (pos < CAP1)
                bins1[(size_t)sb * CAP1 + pos] = r4.y | ((c4.y & 4095u) << 18);
        }
        {
            int sb = (int)(c4.z >> SBSH);
            int pos = lbase[sb] + atomicAdd(&ofs[sb], 1);
            if (pos < CAP1)
                bins1[(size_t)sb * CAP1 + pos] = r4.z | ((c4.z & 4095u) << 18);
        }
        {
            int sb = (int)(c4.w >> SBSH);
            int pos = lbase[sb] + atomicAdd(&ofs[sb], 1);
            if (pos < CAP1)
                bins1[(size_t)sb * CAP1 + pos] = r4.w | ((c4.w & 4095u) << 18);
        }
    }
    for (int e = (nv << 2) + t; e < n; e += 256) {
        unsigned c = cstage[e];
        int sb = (int)(c >> SBSH);
        int pos = lbase[sb] + atomicAdd(&ofs[sb], 1);
        if (pos < CAP1)
            bins1[(size_t)sb * CAP1 + pos] = (unsigned)row[cb + e] | ((c & 4095u) << 18);
    }
}

// ---------- pass 2: split each super-bucket into 16 fine buckets ----------
// uint4-vectorized bins1 stream (head/tail alignment handled; R3-validated form)
__global__ void k_part2(const unsigned* __restrict__ bins1, const int* __restrict__ cursor1,
                        int* __restrict__ cursor2, unsigned* __restrict__ bins2) {
    __shared__ int hist4[4][17];   // 4 wave-quarter copies, padded
    __shared__ int lbase[16];
    __shared__ int ofs[16];
    int t = threadIdx.x;
    int sb = blockIdx.x >> 4;
    int sp = blockIdx.x & 15;
    int cnt = cursor1[sb * 16];
    if (cnt > CAP1) cnt = CAP1;
    int s0 = sb * CAP1;
    int js = s0 + (int)(((long long)cnt * sp) / S2);
    int je = s0 + (int)(((long long)cnt * (sp + 1)) / S2);
    int ja = (js + 3) & ~3;                // first 16B-aligned record
    if (ja > je) ja = je;
    int jv = ja + (((je - ja) >> 2) << 2); // end of full uint4 groups
    if (t < 16) { hist4[0][t] = 0; hist4[1][t] = 0; hist4[2][t] = 0; hist4[3][t] = 0; }
    __syncthreads();
    int cp = (t >> 4) & 3;
    if (t < ja - js) atomicAdd(&hist4[cp][bins1[js + t] >> 26], 1);
    for (int j = ja + (t << 2); j < jv; j += 1024) {
        uint4 rr = *reinterpret_cast<const uint4*>(bins1 + j);
        atomicAdd(&hist4[cp][rr.x >> 26], 1);
        atomicAdd(&hist4[cp][rr.y >> 26], 1);
        atomicAdd(&hist4[cp][rr.z >> 26], 1);
        atomicAdd(&hist4[cp][rr.w >> 26], 1);
    }
    for (int j = jv + t; j < je; j += 256)
        atomicAdd(&hist4[cp][bins1[j] >> 26], 1);
    __syncthreads();
    if (t < 16) {
        int h = hist4[0][t] + hist4[1][t] + hist4[2][t] + hist4[3][t];
        lbase[t] = h ? atomicAdd(&cursor2[(sb * 16 + t) * 16], h) : 0;
        ofs[t] = 0;
    }
    __syncthreads();
    if (t < ja - js) {
        unsigned rec = bins1[js + t];
        int fl = rec >> 26;
        int pos = lbase[fl] + atomicAdd(&ofs[fl], 1);
        if (pos < CAP2)
            bins2[(size_t)(sb * 16 + fl) * CAP2 + pos] =
                (rec & SMASK) | (((rec >> 18) & 255u) << 18);
    }
    for (int j = ja + (t << 2); j < jv; j += 1024) {
        uint4 rr = *reinterpret_cast<const uint4*>(bins1 + j);
        #pragma unroll
        for (int q = 0; q < 4; ++q) {
            unsigned rec = (q == 0) ? rr.x : (q == 1) ? rr.y : (q == 2) ? rr.z : rr.w;
            int fl = rec >> 26;
            int pos = lbase[fl] + atomicAdd(&ofs[fl], 1);
            if (pos < CAP2)
                bins2[(size_t)(sb * 16 + fl) * CAP2 + pos] =
                    (rec & SMASK) | (((rec >> 18) & 255u) << 18);
        }
    }
    for (int j = jv + t; j < je; j += 256) {
        unsigned rec = bins1[j];
        int fl = rec >> 26;
        int pos = lbase[fl] + atomicAdd(&ofs[fl], 1);
        if (pos < CAP2)
            bins2[(size_t)(sb * 16 + fl) * CAP2 + pos] =
                (rec & SMASK) | (((rec >> 18) & 255u) << 18);
    }
}

// ---------- fused degree + dinv + dx (per fine bucket) ----------
__global__ void k_degdx(const unsigned* __restrict__ bins, const int* __restrict__ cursor,
                        const float* __restrict__ x,
                        float* __restrict__ dinv, float* __restrict__ dx, int N) {
    __shared__ int cnt[BSZ];
    int t = threadIdx.x, b = blockIdx.x;
    cnt[t] = 0;
    __syncthreads();
    int m = cursor[b * 16];
    if (m > CAP2) m = CAP2;
    int s = b * CAP2, e = s + m;
    int full = ((e - s) >> 10) << 10;
    int ev = s + full;
    for (int j = s + (t << 2); j < ev; j += 1024) {
        uint4 rr = *reinterpret_cast<const uint4*>(bins + j);
        atomicAdd(&cnt[rr.x >> 18], 1);
        atomicAdd(&cnt[rr.y >> 18], 1);
        atomicAdd(&cnt[rr.z >> 18], 1);
        atomicAdd(&cnt[rr.w >> 18], 1);
    }
    for (int j = ev + t; j < e; j += 256) atomicAdd(&cnt[bins[j] >> 18], 1);
    __syncthreads();
    int node = (b << BSH) + t;
    if (node < N) {
        float d = rsqrtf((float)(cnt[t] + 1));
        dinv[node] = d;
        dx[node] = d * x[node];
    }
}

// ---------- layer-1 scalar aggregate (per fine bucket) ----------
// epilogue classifies each node's S into its relu interval k and packs k
// into the low 5 mantissa bits of dinv (error ~2e-6 rel, tolerance 1e-3)
__global__ void k_s1(const unsigned* __restrict__ bins, const int* __restrict__ cursor,
                     const float* __restrict__ dinv, const float* __restrict__ dx,
                     const float* __restrict__ ts,
                     float2* __restrict__ gpq, int N) {
    __shared__ float sacc[BSZ];
    int t = threadIdx.x, b = blockIdx.x;
    sacc[t] = 0.0f;
    __syncthreads();
    int m = cursor[b * 16];
    if (m > CAP2) m = CAP2;
    int s = b * CAP2, e = s + m;
    int full = ((e - s) >> 10) << 10;
    int ev = s + full;
    for (int j = s + (t << 2); j < ev; j += 1024) {
        uint4 rr = *reinterpret_cast<const uint4*>(bins + j);
        float v0 = dx[rr.x & SMASK], v1 = dx[rr.y & SMASK],
              v2 = dx[rr.z & SMASK], v3 = dx[rr.w & SMASK];
        atomicAdd(&sacc[rr.x >> 18], v0);
        atomicAdd(&sacc[rr.y >> 18], v1);
        atomicAdd(&sacc[rr.z >> 18], v2);
        atomicAdd(&sacc[rr.w >> 18], v3);
    }
    for (int j = ev + t; j < e; j += 256) {
        unsigned r = bins[j];
        atomicAdd(&sacc[r >> 18], dx[r & SMASK]);
    }
    __syncthreads();
    int node = (b << BSH) + t;
    if (node < N) {
        float d = dinv[node];
        float S = d * (sacc[t] + dx[node]);   // + self-loop dinv^2*x
        int k = 0;
        #pragma unroll
        for (int g = 0; g < HD; ++g) k += (S > ts[g]);
        unsigned dq = (__float_as_uint(d) & ~31u) | (unsigned)k;
        gpq[node] = make_float2(d * S, __uint_as_float(dq));
    }
}

// ---------- layer-2: interval-bucketed LDS aggregate + fused recon/epilogue ----------
// 512 threads, 35.8 KB LDS: 4 blocks/CU x 8 waves = 32 waves/CU.
// Pinned at ~60.5 us by its compulsory 20.4 MB at ~343 GB/s effective (R7 analysis).
__global__ void __launch_bounds__(AGT, 1)
k_agg(const unsigned* __restrict__ bins, const int* __restrict__ cursor,
      const float2* __restrict__ gpq, const float* __restrict__ dinv,
      const int* __restrict__ splits, const int* __restrict__ signs,
      const float* __restrict__ W1, const float* __restrict__ b1,
      const float* __restrict__ W2, const float* __restrict__ b2,
      const float* __restrict__ Wfc, const float* __restrict__ bfc,
      float* __restrict__ out, int N) {
    __shared__ float acc[BSZ * STR];   // 35.8 KB
    int t = threadIdx.x, b = blockIdx.x;
    for (int i = t; i < BSZ * STR; i += AGT) acc[i] = 0.0f;
    __syncthreads();

    int m = cursor[b * 16];
    if (m > CAP2) m = CAP2;
    int s = b * CAP2, e = s + m;
    int nv = m >> 2;                       // full uint4 groups (s is 16B-aligned)
    const uint4* b4 = reinterpret_cast<const uint4*>(bins + s);
    for (int i = t; i < nv; i += AGT) {
        uint4 rr = b4[i];
        float2 p0 = gpq[rr.x & SMASK], p1 = gpq[rr.y & SMASK],
               p2 = gpq[rr.z & SMASK], p3 = gpq[rr.w & SMASK];
        float* a0 = &acc[(int)(rr.x >> 18) * STR + 2 * (int)(__float_as_uint(p0.y) & 31u)];
        float* a1 = &acc[(int)(rr.y >> 18) * STR + 2 * (int)(__float_as_uint(p1.y) & 31u)];
        float* a2 = &acc[(int)(rr.z >> 18) * STR + 2 * (int)(__float_as_uint(p2.y) & 31u)];
        float* a3 = &acc[(int)(rr.w >> 18) * STR + 2 * (int)(__float_as_uint(p3.y) & 31u)];
        atomicAdd(a0, p0.x); atomicAdd(a0 + 1, p0.y);
        atomicAdd(a1, p1.x); atomicAdd(a1 + 1, p1.y);
        atomicAdd(a2, p2.x); atomicAdd(a2 + 1, p2.y);
        atomicAdd(a3, p3.x); atomicAdd(a3 + 1, p3.y);
    }
    for (int j = s + (nv << 2) + t; j < e; j += AGT) {
        unsigned r = bins[j];
        float2 p = gpq[r & SMASK];
        float* a = &acc[(int)(r >> 18) * STR + 2 * (int)(__float_as_uint(p.y) & 31u)];
        atomicAdd(a, p.x); atomicAdd(a + 1, p.y);
    }
    __syncthreads();

    // ---- reconstruction + epilogue (first 256 lanes; one node each) ----
    int node = (b << BSH) + t;
    if (t >= BSZ || node >= N) return;
    float Ppre[NIV + 1], Qpre[NIV + 1];
    float pp = 0.0f, qq = 0.0f;
    #pragma unroll
    for (int mm = 0; mm < NIV; ++mm) {
        Ppre[mm] = pp; Qpre[mm] = qq;
        pp += acc[t * STR + 2 * mm];
        qq += acc[t * STR + 2 * mm + 1];
    }
    Ppre[NIV] = pp; Qpre[NIV] = qq;

    float2 pq = gpq[node];
    float di = dinv[node];        // exact dinv (gpq.y carries packed k bits)
    float si = pq.x / di;         // S = (d*S)/d
    float aggv[HD];
    #pragma unroll
    for (int f = 0; f < HD; ++f) {
        int sp = splits[f], sg = signs[f];
        float w = W1[f], bb = b1[f];
        float A, B;
        if (sg > 0)      { A = pp - Ppre[sp]; B = qq - Qpre[sp]; }
        else if (sg < 0) { A = Ppre[sp];      B = Qpre[sp]; }
        else             { A = 0.0f;          B = (bb > 0.0f) ? qq : 0.0f; }
        float selfh = fmaxf(fmaf(w, si, bb), 0.0f);
        aggv[f] = di * (fmaf(w, A, bb * B) + di * selfh);
    }
    float o0 = bfc[0], o1 = bfc[1], o2 = bfc[2], o3 = bfc[3];
    #pragma unroll
    for (int f2 = 0; f2 < HD; ++f2) {
        float h = b2[f2];
        #pragma unroll
        for (int k = 0; k < HD; ++k) h = fmaf(aggv[k], W2[k * HD + f2], h);
        h = fmaxf(h, 0.0f);
        o0 = fmaf(h, Wfc[f2 * NC + 0], o0);
        o1 = fmaf(h, Wfc[f2 * NC + 1], o1);
        o2 = fmaf(h, Wfc[f2 * NC + 2], o2);
        o3 = fmaf(h, Wfc[f2 * NC + 3], o3);
    }
    ((float4*)out)[node] = make_float4(o0, o1, o2, o3);
}

extern "C" void kernel_launch(void* const* d_in, const int* in_sizes, int n_in,
                              void* d_out, int out_size, void* d_ws, size_t ws_size,
                              hipStream_t stream) {
    const float* x   = (const float*)d_in[0];
    const int*   ei  = (const int*)d_in[1];
    const float* W1  = (const float*)d_in[2];
    const float* b1  = (const float*)d_in[3];
    const float* W2  = (const float*)d_in[4];
    const float* b2  = (const float*)d_in[5];
    const float* Wfc = (const float*)d_in[6];
    const float* bfc = (const float*)d_in[7];
    float* out = (float*)d_out;

    const int N = in_sizes[0];            // 250000 (< 2^18)
    const int E = in_sizes[1] / 2;        // 4000000
    const int* row = ei;
    const int* col = ei + E;

    // workspace layout (~43 MB)
    char* ws = (char*)d_ws;
    size_t off = 0;
    unsigned* bins1 = (unsigned*)(ws + off); off += (size_t)NSB * CAP1 * 4;   // 17.8 MB
    unsigned* bins2 = (unsigned*)(ws + off); off += (size_t)NFB * CAP2 * 4;   // 21 MB
    int*    cursor1= (int*)(ws + off);   off += (size_t)NSB * 16 * 4;         // 4 KB   } contiguous,
    int*    cursor2= (int*)(ws + off);   off += (size_t)NFB * 16 * 4;         // 64 KB  } zeroed in k_thr
    float*  dinv  = (float*)(ws + off);  off += (size_t)N * 4;
    float*  dx    = (float*)(ws + off);  off += (size_t)N * 4;
    float2* gpq   = (float2*)(ws + off); off += (size_t)N * 8;                // (d*S, d|k)
    float*  ts    = (float*)(ws + off);  off += 64;
    int*    splits= (int*)(ws + off);    off += 64;
    int*    signs = (int*)(ws + off);    off += 64;

    const int B = 256;
    k_thr<<<1, B, 0, stream>>>(W1, b1, ts, splits, signs,
                               cursor1, (NSB + NFB) * 16);
    const int G1 = 1024;
    int CHK = (E + G1 - 1) / G1;
    CHK = (CHK + 3) & ~3;                 // 4-aligned chunks; CHK=3908 <= CHKMAX
    k_part1<<<G1, B, 0, stream>>>(row, col, cursor1, bins1, E, CHK);
    k_part2<<<NSB * S2, B, 0, stream>>>(bins1, cursor1, cursor2, bins2);
    k_degdx<<<NFB, B, 0, stream>>>(bins2, cursor2, x, dinv, dx, N);
    k_s1<<<NFB, B, 0, stream>>>(bins2, cursor2, dinv, dx, ts, gpq, N);
    k_agg<<<NFB, AGT, 0, stream>>>(bins2, cursor2, gpq, dinv, splits, signs,
                                   W1, b1, W2, b2, Wfc, bfc, out, N);
}

// Round 11
// 221.654 us; speedup vs baseline: 1.1961x; 1.0362x over previous
//
#include <hip/hip_runtime.h>
#include <math.h>

#define HD 16      // hidden dim
#define NC 4       // num classes
#define BSH 8      // log2(nodes per fine bucket)
#define BSZ 256    // nodes per fine bucket
#define NSB 64     // super-buckets (64 * 4096 = 262144 >= N)
#define SBSH 12    // log2(nodes per super-bucket)
#define CAP1 69632 // per-super-bucket capacity (mean 65536 + 16 sigma)
#define CAP2 5120  // per-fine-bucket capacity (mean 4096 + 16 sigma)
#define S2 16      // splits per super-bucket in pass 2
#define NFB 1024   // fine buckets total (NSB * 16)
#define NIV 17     // intervals = HD + 1
#define STR 35     // LDS P/Q row stride per node (odd -> conflict-free)
#define AGT 512    // k_agg threads (4 blocks/CU x 512 = 2048 = 100% thread slots)
#define CHKMAX 4096 // max edges per part1 block (CHK=3908 fits)
#define SMASK 0x3FFFFu  // low 18 bits = src id

// ext_vector types: __builtin_nontemporal_* accepts these (not HIP_vector_type)
typedef unsigned uint4e __attribute__((ext_vector_type(4)));
typedef float    float4e __attribute__((ext_vector_type(4)));

// ---------- prep: zero cursors + sorted relu thresholds + split/sign ----------
__global__ void k_thr(const float* __restrict__ W1, const float* __restrict__ b1,
                      float* __restrict__ ts, int* __restrict__ splits,
                      int* __restrict__ signs, int* __restrict__ cursors, int ncur) {
    int t = threadIdx.x;
    for (int i = t; i < ncur; i += 256) cursors[i] = 0;
    if (t != 0) return;
    float tt[HD], s[HD];
    for (int f = 0; f < HD; ++f) {
        float w = W1[f];
        tt[f] = (w != 0.0f) ? (-b1[f] / w) : INFINITY;
        s[f] = tt[f];
    }
    for (int i = 1; i < HD; ++i) {            // insertion sort
        float key = s[i]; int j = i - 1;
        while (j >= 0 && s[j] > key) { s[j + 1] = s[j]; --j; }
        s[j + 1] = key;
    }
    for (int f = 0; f < HD; ++f) ts[f] = s[f];
    for (int f = 0; f < HD; ++f) {
        float w = W1[f];
        if (w == 0.0f) { signs[f] = 0; splits[f] = 0; continue; }
        int c = 0;
        for (int g = 0; g < HD; ++g) c += (s[g] < tt[f]) ? 1 : 0;
        splits[f] = c + 1;                    // prefix index
        signs[f] = (w > 0.0f) ? 1 : -1;
    }
}

// ---------- pass 1: partition edges into 64 super-buckets (R8 champion form) ----------
__global__ void k_part1(const int* __restrict__ row, const int* __restrict__ col,
                        int* __restrict__ cursor1, unsigned* __restrict__ bins1,
                        int E, int CHK) {
    __shared__ int hist4[4][NSB + 1];
    __shared__ int lbase[NSB];
    __shared__ int ofs[NSB];
    __shared__ unsigned cstage[CHKMAX];   // 16 KB col stage
    int t = threadIdx.x;
    int cb = blockIdx.x * CHK;
    int ce = min(E, cb + CHK);
    if (cb >= ce) return;
    int n = ce - cb;
    int nv = n >> 2;                       // uint4 groups (cb is 4-aligned)
    const uint4* col4 = reinterpret_cast<const uint4*>(col + cb);
    const uint4* row4 = reinterpret_cast<const uint4*>(row + cb);
    int cp = (t >> 4) & 3;
    if (t < NSB) { hist4[0][t] = 0; hist4[1][t] = 0; hist4[2][t] = 0; hist4[3][t] = 0; }
    __syncthreads();
    for (int i = t; i < nv; i += 256) {
        uint4 c4 = col4[i];
        reinterpret_cast<uint4*>(cstage)[i] = c4;
        atomicAdd(&hist4[cp][c4.x >> SBSH], 1);
        atomicAdd(&hist4[cp][c4.y >> SBSH], 1);
        atomicAdd(&hist4[cp][c4.z >> SBSH], 1);
        atomicAdd(&hist4[cp][c4.w >> SBSH], 1);
    }
    for (int e = (nv << 2) + t; e < n; e += 256) {
        unsigned c = (unsigned)col[cb + e];
        cstage[e] = c;
        atomicAdd(&hist4[cp][c >> SBSH], 1);
    }
    __syncthreads();
    if (t < NSB) {
        int h = hist4[0][t] + hist4[1][t] + hist4[2][t] + hist4[3][t];
        lbase[t] = h ? atomicAdd(&cursor1[t * 16], h) : 0;
        ofs[t] = 0;
    }
    __syncthreads();
    for (int i = t; i < nv; i += 256) {
        uint4 r4 = row4[i];
        uint4 c4 = reinterpret_cast<const uint4*>(cstage)[i];   // LDS, b128
        {
            int sb = (int)(c4.x >> SBSH);
            int pos = lbase[sb] + atomicAdd(&ofs[sb], 1);
            if (pos < CAP1)
                bins1[(size_t)sb * CAP1 + pos] = r4.x | ((c4.x & 4095u) << 18);
        }
        {
            int sb = (int)(c4.y >> SBSH);
            int pos = lbase[sb] + atomicAdd(&ofs[sb], 1);
            if (pos < CAP1)
                bins1[(size_t)sb * CAP1 + pos] = r4.y | ((c4.y & 4095u) << 18);
        }
        {
            int sb = (int)(c4.z >> SBSH);
            int pos = lbase[sb] + atomicAdd(&ofs[sb], 1);
            if (pos < CAP1)
                bins1[(size_t)sb * CAP1 + pos] = r4.z | ((c4.z & 4095u) << 18);
        }
        {
            int sb = (int)(c4.w >> SBSH);
            int pos = lbase[sb] + atomicAdd(&ofs[sb], 1);
            if (pos < CAP1)
                bins1[(size_t)sb * CAP1 + pos] = r4.w | ((c4.w & 4095u) << 18);
        }
    }
    for (int e = (nv << 2) + t; e < n; e += 256) {
        unsigned c = cstage[e];
        int sb = (int)(c >> SBSH);
        int pos = lbase[sb] + atomicAdd(&ofs[sb], 1);
        if (pos < CAP1)
            bins1[(size_t)sb * CAP1 + pos] = (unsigned)row[cb + e] | ((c & 4095u) << 18);
    }
}

// ---------- pass 2: split each super-bucket into 16 fine buckets (R8 champion form) ----------
// (normal loads: the scatter phase re-reads the slice the hist phase fetched -> L2 reuse)
__global__ void k_part2(const unsigned* __restrict__ bins1, const int* __restrict__ cursor1,
                        int* __restrict__ cursor2, unsigned* __restrict__ bins2) {
    __shared__ int hist4[4][17];   // 4 wave-quarter copies, padded
    __shared__ int lbase[16];
    __shared__ int ofs[16];
    int t = threadIdx.x;
    int sb = blockIdx.x >> 4;
    int sp = blockIdx.x & 15;
    int cnt = cursor1[sb * 16];
    if (cnt > CAP1) cnt = CAP1;
    int s0 = sb * CAP1;
    int js = s0 + (int)(((long long)cnt * sp) / S2);
    int je = s0 + (int)(((long long)cnt * (sp + 1)) / S2);
    int ja = (js + 3) & ~3;                // first 16B-aligned record
    if (ja > je) ja = je;
    int jv = ja + (((je - ja) >> 2) << 2); // end of full uint4 groups
    if (t < 16) { hist4[0][t] = 0; hist4[1][t] = 0; hist4[2][t] = 0; hist4[3][t] = 0; }
    __syncthreads();
    int cp = (t >> 4) & 3;
    if (t < ja - js) atomicAdd(&hist4[cp][bins1[js + t] >> 26], 1);
    for (int j = ja + (t << 2); j < jv; j += 1024) {
        uint4 rr = *reinterpret_cast<const uint4*>(bins1 + j);
        atomicAdd(&hist4[cp][rr.x >> 26], 1);
        atomicAdd(&hist4[cp][rr.y >> 26], 1);
        atomicAdd(&hist4[cp][rr.z >> 26], 1);
        atomicAdd(&hist4[cp][rr.w >> 26], 1);
    }
    for (int j = jv + t; j < je; j += 256)
        atomicAdd(&hist4[cp][bins1[j] >> 26], 1);
    __syncthreads();
    if (t < 16) {
        int h = hist4[0][t] + hist4[1][t] + hist4[2][t] + hist4[3][t];
        lbase[t] = h ? atomicAdd(&cursor2[(sb * 16 + t) * 16], h) : 0;
        ofs[t] = 0;
    }
    __syncthreads();
    if (t < ja - js) {
        unsigned rec = bins1[js + t];
        int fl = rec >> 26;
        int pos = lbase[fl] + atomicAdd(&ofs[fl], 1);
        if (pos < CAP2)
            bins2[(size_t)(sb * 16 + fl) * CAP2 + pos] =
                (rec & SMASK) | (((rec >> 18) & 255u) << 18);
    }
    for (int j = ja + (t << 2); j < jv; j += 1024) {
        uint4 rr = *reinterpret_cast<const uint4*>(bins1 + j);
        #pragma unroll
        for (int q = 0; q < 4; ++q) {
            unsigned rec = (q == 0) ? rr.x : (q == 1) ? rr.y : (q == 2) ? rr.z : rr.w;
            int fl = rec >> 26;
            int pos = lbase[fl] + atomicAdd(&ofs[fl], 1);
            if (pos < CAP2)
                bins2[(size_t)(sb * 16 + fl) * CAP2 + pos] =
                    (rec & SMASK) | (((rec >> 18) & 255u) << 18);
        }
    }
    for (int j = jv + t; j < je; j += 256) {
        unsigned rec = bins1[j];
        int fl = rec >> 26;
        int pos = lbase[fl] + atomicAdd(&ofs[fl], 1);
        if (pos < CAP2)
            bins2[(size_t)(sb * 16 + fl) * CAP2 + pos] =
                (rec & SMASK) | (((rec >> 18) & 255u) << 18);
    }
}

// ---------- fused degree + dinv + dx (per fine bucket) ----------
// bins2 stream is non-temporal: evict-first, keeps L2 clean for gather arrays.
__global__ void k_degdx(const unsigned* __restrict__ bins, const int* __restrict__ cursor,
                        const float* __restrict__ x,
                        float* __restrict__ dinv, float* __restrict__ dx, int N) {
    __shared__ int cnt[BSZ];
    int t = threadIdx.x, b = blockIdx.x;
    cnt[t] = 0;
    __syncthreads();
    int m = cursor[b * 16];
    if (m > CAP2) m = CAP2;
    int s = b * CAP2, e = s + m;
    int full = ((e - s) >> 10) << 10;
    int ev = s + full;
    for (int j = s + (t << 2); j < ev; j += 1024) {
        uint4e rr = __builtin_nontemporal_load(reinterpret_cast<const uint4e*>(bins + j));
        atomicAdd(&cnt[rr[0] >> 18], 1);
        atomicAdd(&cnt[rr[1] >> 18], 1);
        atomicAdd(&cnt[rr[2] >> 18], 1);
        atomicAdd(&cnt[rr[3] >> 18], 1);
    }
    for (int j = ev + t; j < e; j += 256)
        atomicAdd(&cnt[__builtin_nontemporal_load(bins + j) >> 18], 1);
    __syncthreads();
    int node = (b << BSH) + t;
    if (node < N) {
        float d = rsqrtf((float)(cnt[t] + 1));
        dinv[node] = d;
        dx[node] = d * x[node];
    }
}

// ---------- layer-1 scalar aggregate (per fine bucket) ----------
// bins2 stream non-temporal so the dx gather array (1 MB) stays L2-resident.
__global__ void k_s1(const unsigned* __restrict__ bins, const int* __restrict__ cursor,
                     const float* __restrict__ dinv, const float* __restrict__ dx,
                     const float* __restrict__ ts,
                     float2* __restrict__ gpq, int N) {
    __shared__ float sacc[BSZ];
    int t = threadIdx.x, b = blockIdx.x;
    sacc[t] = 0.0f;
    __syncthreads();
    int m = cursor[b * 16];
    if (m > CAP2) m = CAP2;
    int s = b * CAP2, e = s + m;
    int full = ((e - s) >> 10) << 10;
    int ev = s + full;
    for (int j = s + (t << 2); j < ev; j += 1024) {
        uint4e rr = __builtin_nontemporal_load(reinterpret_cast<const uint4e*>(bins + j));
        float v0 = dx[rr[0] & SMASK], v1 = dx[rr[1] & SMASK],
              v2 = dx[rr[2] & SMASK], v3 = dx[rr[3] & SMASK];
        atomicAdd(&sacc[rr[0] >> 18], v0);
        atomicAdd(&sacc[rr[1] >> 18], v1);
        atomicAdd(&sacc[rr[2] >> 18], v2);
        atomicAdd(&sacc[rr[3] >> 18], v3);
    }
    for (int j = ev + t; j < e; j += 256) {
        unsigned r = __builtin_nontemporal_load(bins + j);
        atomicAdd(&sacc[r >> 18], dx[r & SMASK]);
    }
    __syncthreads();
    int node = (b << BSH) + t;
    if (node < N) {
        float d = dinv[node];
        float S = d * (sacc[t] + dx[node]);   // + self-loop dinv^2*x
        int k = 0;
        #pragma unroll
        for (int g = 0; g < HD; ++g) k += (S > ts[g]);
        unsigned dq = (__float_as_uint(d) & ~31u) | (unsigned)k;
        gpq[node] = make_float2(d * S, __uint_as_float(dq));
    }
}

// ---------- layer-2: interval-bucketed LDS aggregate + fused recon/epilogue ----------
// bins2 stream non-temporal so the gpq gather array (2 MB) stays L2-resident
// (R10 theory: stream was evicting gpq -> 4M x 128B L3 line fills ~= the 60us).
// Output store non-temporal (write-once).
__global__ void __launch_bounds__(AGT, 1)
k_agg(const unsigned* __restrict__ bins, const int* __restrict__ cursor,
      const float2* __restrict__ gpq, const float* __restrict__ dinv,
      const int* __restrict__ splits, const int* __restrict__ signs,
      const float* __restrict__ W1, const float* __restrict__ b1,
      const float* __restrict__ W2, const float* __restrict__ b2,
      const float* __restrict__ Wfc, const float* __restrict__ bfc,
      float* __restrict__ out, int N) {
    __shared__ float acc[BSZ * STR];   // 35.8 KB
    int t = threadIdx.x, b = blockIdx.x;
    for (int i = t; i < BSZ * STR; i += AGT) acc[i] = 0.0f;
    __syncthreads();

    int m = cursor[b * 16];
    if (m > CAP2) m = CAP2;
    int s = b * CAP2, e = s + m;
    int nv = m >> 2;                       // full uint4 groups (s is 16B-aligned)
    const uint4e* b4 = reinterpret_cast<const uint4e*>(bins + s);
    for (int i = t; i < nv; i += AGT) {
        uint4e rr = __builtin_nontemporal_load(b4 + i);
        float2 p0 = gpq[rr[0] & SMASK], p1 = gpq[rr[1] & SMASK],
               p2 = gpq[rr[2] & SMASK], p3 = gpq[rr[3] & SMASK];
        float* a0 = &acc[(int)(rr[0] >> 18) * STR + 2 * (int)(__float_as_uint(p0.y) & 31u)];
        float* a1 = &acc[(int)(rr[1] >> 18) * STR + 2 * (int)(__float_as_uint(p1.y) & 31u)];
        float* a2 = &acc[(int)(rr[2] >> 18) * STR + 2 * (int)(__float_as_uint(p2.y) & 31u)];
        float* a3 = &acc[(int)(rr[3] >> 18) * STR + 2 * (int)(__float_as_uint(p3.y) & 31u)];
        atomicAdd(a0, p0.x); atomicAdd(a0 + 1, p0.y);
        atomicAdd(a1, p1.x); atomicAdd(a1 + 1, p1.y);
        atomicAdd(a2, p2.x); atomicAdd(a2 + 1, p2.y);
        atomicAdd(a3, p3.x); atomicAdd(a3 + 1, p3.y);
    }
    for (int j = s + (nv << 2) + t; j < e; j += AGT) {
        unsigned r = __builtin_nontemporal_load(bins + j);
        float2 p = gpq[r & SMASK];
        float* a = &acc[(int)(r >> 18) * STR + 2 * (int)(__float_as_uint(p.y) & 31u)];
        atomicAdd(a, p.x); atomicAdd(a + 1, p.y);
    }
    __syncthreads();

    // ---- reconstruction + epilogue (first 256 lanes; one node each) ----
    int node = (b << BSH) + t;
    if (t >= BSZ || node >= N) return;
    float Ppre[NIV + 1], Qpre[NIV + 1];
    float pp = 0.0f, qq = 0.0f;
    #pragma unroll
    for (int mm = 0; mm < NIV; ++mm) {
        Ppre[mm] = pp; Qpre[mm] = qq;
        pp += acc[t * STR + 2 * mm];
        qq += acc[t * STR + 2 * mm + 1];
    }
    Ppre[NIV] = pp; Qpre[NIV] = qq;

    float2 pq = gpq[node];
    float di = dinv[node];        // exact dinv (gpq.y carries packed k bits)
    float si = pq.x / di;         // S = (d*S)/d
    float aggv[HD];
    #pragma unroll
    for (int f = 0; f < HD; ++f) {
        int sp = splits[f], sg = signs[f];
        float w = W1[f], bb = b1[f];
        float A, B;
        if (sg > 0)      { A = pp - Ppre[sp]; B = qq - Qpre[sp]; }
        else if (sg < 0) { A = Ppre[sp];      B = Qpre[sp]; }
        else             { A = 0.0f;          B = (bb > 0.0f) ? qq : 0.0f; }
        float selfh = fmaxf(fmaf(w, si, bb), 0.0f);
        aggv[f] = di * (fmaf(w, A, bb * B) + di * selfh);
    }
    float o0 = bfc[0], o1 = bfc[1], o2 = bfc[2], o3 = bfc[3];
    #pragma unroll
    for (int f2 = 0; f2 < HD; ++f2) {
        float h = b2[f2];
        #pragma unroll
        for (int k = 0; k < HD; ++k) h = fmaf(aggv[k], W2[k * HD + f2], h);
        h = fmaxf(h, 0.0f);
        o0 = fmaf(h, Wfc[f2 * NC + 0], o0);
        o1 = fmaf(h, Wfc[f2 * NC + 1], o1);
        o2 = fmaf(h, Wfc[f2 * NC + 2], o2);
        o3 = fmaf(h, Wfc[f2 * NC + 3], o3);
    }
    float4e ov = { o0, o1, o2, o3 };
    __builtin_nontemporal_store(ov, reinterpret_cast<float4e*>(out) + node);
}

extern "C" void kernel_launch(void* const* d_in, const int* in_sizes, int n_in,
                              void* d_out, int out_size, void* d_ws, size_t ws_size,
                              hipStream_t stream) {
    const float* x   = (const float*)d_in[0];
    const int*   ei  = (const int*)d_in[1];
    const float* W1  = (const float*)d_in[2];
    const float* b1  = (const float*)d_in[3];
    const float* W2  = (const float*)d_in[4];
    const float* b2  = (const float*)d_in[5];
    const float* Wfc = (const float*)d_in[6];
    const float* bfc = (const float*)d_in[7];
    float* out = (float*)d_out;

    const int N = in_sizes[0];            // 250000 (< 2^18)
    const int E = in_sizes[1] / 2;        // 4000000
    const int* row = ei;
    const int* col = ei + E;

    // workspace layout (~43 MB)
    char* ws = (char*)d_ws;
    size_t off = 0;
    unsigned* bins1 = (unsigned*)(ws + off); off += (size_t)NSB * CAP1 * 4;   // 17.8 MB
    unsigned* bins2 = (unsigned*)(ws + off); off += (size_t)NFB * CAP2 * 4;   // 21 MB
    int*    cursor1= (int*)(ws + off);   off += (size_t)NSB * 16 * 4;         // 4 KB   } contiguous,
    int*    cursor2= (int*)(ws + off);   off += (size_t)NFB * 16 * 4;         // 64 KB  } zeroed in k_thr
    float*  dinv  = (float*)(ws + off);  off += (size_t)N * 4;
    float*  dx    = (float*)(ws + off);  off += (size_t)N * 4;
    float2* gpq   = (float2*)(ws + off); off += (size_t)N * 8;                // (d*S, d|k)
    float*  ts    = (float*)(ws + off);  off += 64;
    int*    splits= (int*)(ws + off);    off += 64;
    int*    signs = (int*)(ws + off);    off += 64;

    const int B = 256;
    k_thr<<<1, B, 0, stream>>>(W1, b1, ts, splits, signs,
                               cursor1, (NSB + NFB) * 16);
    const int G1 = 1024;
    int CHK = (E + G1 - 1) / G1;
    CHK = (CHK + 3) & ~3;                 // 4-aligned chunks; CHK=3908 <= CHKMAX
    k_part1<<<G1, B, 0, stream>>>(row, col, cursor1, bins1, E, CHK);
    k_part2<<<NSB * S2, B, 0, stream>>>(bins1, cursor1, cursor2, bins2);
    k_degdx<<<NFB, B, 0, stream>>>(bins2, cursor2, x, dinv, dx, N);
    k_s1<<<NFB, B, 0, stream>>>(bins2, cursor2, dinv, dx, ts, gpq, N);
    k_agg<<<NFB, AGT, 0, stream>>>(bins2, cursor2, gpq, dinv, splits, signs,
                                   W1, b1, W2, b2, Wfc, bfc, out, N);
}

// Round 13
// 209.622 us; speedup vs baseline: 1.2647x; 1.0574x over previous
//
#include <hip/hip_runtime.h>
#include <math.h>

#define HD 16      // hidden dim
#define NC 4       // num classes
#define BSH 8      // log2(nodes per fine bucket)
#define BSZ 256    // nodes per fine bucket
#define NSB 64     // super-buckets (64 * 4096 = 262144 >= N)
#define SBSH 12    // log2(nodes per super-bucket)
#define NB1 1024   // part1 blocks (fixed: region index uses 10 bits)
#define CAPB 128   // per-(block,sb) region capacity (lambda=61; P(ovf)~5e-8; pow2 -> shifts)
#define CAP2 5120  // per-fine-bucket capacity (mean 4096 + 16 sigma)
#define NFB 1024   // fine buckets total (NSB * 16)
#define NIV 17     // intervals = HD + 1
#define STR 35     // LDS P/Q row stride per node (odd -> conflict-free)
#define AGT 512    // k_agg threads (4 blocks/CU x 512 = 2048 = 100% thread slots)
#define SMASK 0x3FFFFu  // low 18 bits = src id

// ext_vector types: __builtin_nontemporal_* accepts these (not HIP_vector_type)
typedef unsigned uint4e __attribute__((ext_vector_type(4)));
typedef float    float4e __attribute__((ext_vector_type(4)));

// ---------- prep: zero cursor2 + sorted relu thresholds + split/sign ----------
__global__ void k_thr(const float* __restrict__ W1, const float* __restrict__ b1,
                      float* __restrict__ ts, int* __restrict__ splits,
                      int* __restrict__ signs, int* __restrict__ cursors, int ncur) {
    int t = threadIdx.x;
    for (int i = t; i < ncur; i += 256) cursors[i] = 0;
    if (t != 0) return;
    float tt[HD], s[HD];
    for (int f = 0; f < HD; ++f) {
        float w = W1[f];
        tt[f] = (w != 0.0f) ? (-b1[f] / w) : INFINITY;
        s[f] = tt[f];
    }
    for (int i = 1; i < HD; ++i) {            // insertion sort
        float key = s[i]; int j = i - 1;
        while (j >= 0 && s[j] > key) { s[j + 1] = s[j]; --j; }
        s[j + 1] = key;
    }
    for (int f = 0; f < HD; ++f) ts[f] = s[f];
    for (int f = 0; f < HD; ++f) {
        float w = W1[f];
        if (w == 0.0f) { signs[f] = 0; splits[f] = 0; continue; }
        int c = 0;
        for (int g = 0; g < HD; ++g) c += (s[g] < tt[f]) ? 1 : 0;
        splits[f] = c + 1;                    // prefix index
        signs[f] = (w > 0.0f) ? 1 : -1;
    }
}

// ---------- pass 1 (single-phase): partition edges into 64 super-buckets ----------
// R13: per-(block,sb) FIXED exclusive regions bins1[sb][b][CAPB] -> no count
// phase, no cursor1, ONE LDS atomic per edge (4M instead of 8M; atomic-pipe
// model says front end is LDS-atomic-throughput bound at ~4cyc/lane-atomic).
// Write runs stay exclusive per block (R4 contiguity lesson respected).
__global__ void k_part1(const int* __restrict__ row, const int* __restrict__ col,
                        int* __restrict__ cnts1, unsigned* __restrict__ bins1,
                        int E, int CHK) {
    __shared__ int ofs[NSB];
    int t = threadIdx.x;
    int b = blockIdx.x;
    int cb = b * CHK;
    int ce = min(E, cb + CHK);
    int n = ce - cb; if (n < 0) n = 0;
    if (t < NSB) ofs[t] = 0;
    __syncthreads();
    int nv = n >> 2;                       // uint4 groups (cb is 4-aligned)
    const uint4* col4 = reinterpret_cast<const uint4*>(col + cb);
    const uint4* row4 = reinterpret_cast<const uint4*>(row + cb);
    for (int i = t; i < nv; i += 256) {
        uint4 c4 = col4[i];
        uint4 r4 = row4[i];
        {
            unsigned c = c4.x; int sb = (int)(c >> SBSH);
            int pos = atomicAdd(&ofs[sb], 1);
            if (pos < CAPB)
                bins1[((((size_t)sb << 10) | b) << 7) + pos] = r4.x | ((c & 4095u) << 18);
        }
        {
            unsigned c = c4.y; int sb = (int)(c >> SBSH);
            int pos = atomicAdd(&ofs[sb], 1);
            if (pos < CAPB)
                bins1[((((size_t)sb << 10) | b) << 7) + pos] = r4.y | ((c & 4095u) << 18);
        }
        {
            unsigned c = c4.z; int sb = (int)(c >> SBSH);
            int pos = atomicAdd(&ofs[sb], 1);
            if (pos < CAPB)
                bins1[((((size_t)sb << 10) | b) << 7) + pos] = r4.z | ((c & 4095u) << 18);
        }
        {
            unsigned c = c4.w; int sb = (int)(c >> SBSH);
            int pos = atomicAdd(&ofs[sb], 1);
            if (pos < CAPB)
                bins1[((((size_t)sb << 10) | b) << 7) + pos] = r4.w | ((c & 4095u) << 18);
        }
    }
    for (int e = (nv << 2) + t; e < n; e += 256) {
        unsigned c = (unsigned)col[cb + e];
        int sb = (int)(c >> SBSH);
        int pos = atomicAdd(&ofs[sb], 1);
        if (pos < CAPB)
            bins1[((((size_t)sb << 10) | b) << 7) + pos] =
                (unsigned)row[cb + e] | ((c & 4095u) << 18);
    }
    __syncthreads();
    if (t < NSB) cnts1[t * NB1 + b] = ofs[t];   // layout cnts1[sb][b]
}

// ---------- pass 2: split each super-bucket into 16 fine buckets ----------
// Reads the 64 fixed segments of its (sb, sp) slice: contiguous 64*CAPB slots,
// invalid slots skipped via count check (pow2 CAPB -> seg=j>>7, pos=j&127).
__global__ void k_part2(const unsigned* __restrict__ bins1, const int* __restrict__ cnts1,
                        int* __restrict__ cursor2, unsigned* __restrict__ bins2) {
    __shared__ int hist4[4][17];   // 4 wave-quarter copies, padded
    __shared__ int lbase[16];
    __shared__ int ofs[16];
    __shared__ int cnt[64];
    int t = threadIdx.x;
    int sb = blockIdx.x >> 4;
    int sp = blockIdx.x & 15;
    if (t < 64) {
        int c = cnts1[sb * NB1 + sp * 64 + t];
        cnt[t] = (c > CAPB) ? CAPB : c;
    }
    if (t < 16) { hist4[0][t] = 0; hist4[1][t] = 0; hist4[2][t] = 0; hist4[3][t] = 0; }
    __syncthreads();
    const unsigned* base = bins1 + ((((size_t)sb << 10) | (sp * 64)) << 7);
    int cp = (t >> 4) & 3;
    for (int j = t << 2; j < 64 * CAPB; j += 1024) {
        uint4 rr = *reinterpret_cast<const uint4*>(base + j);
        int cs = cnt[j >> 7];
        int p0 = j & 127;
        if (p0 + 0 < cs) atomicAdd(&hist4[cp][rr.x >> 26], 1);
        if (p0 + 1 < cs) atomicAdd(&hist4[cp][rr.y >> 26], 1);
        if (p0 + 2 < cs) atomicAdd(&hist4[cp][rr.z >> 26], 1);
        if (p0 + 3 < cs) atomicAdd(&hist4[cp][rr.w >> 26], 1);
    }
    __syncthreads();
    if (t < 16) {
        int h = hist4[0][t] + hist4[1][t] + hist4[2][t] + hist4[3][t];
        lbase[t] = h ? atomicAdd(&cursor2[(sb * 16 + t) * 16], h) : 0;
        ofs[t] = 0;
    }
    __syncthreads();
    for (int j = t << 2; j < 64 * CAPB; j += 1024) {
        uint4 rr = *reinterpret_cast<const uint4*>(base + j);
        int cs = cnt[j >> 7];
        int p0 = j & 127;
        #pragma unroll
        for (int q = 0; q < 4; ++q) {
            if (p0 + q < cs) {
                unsigned rec = (q == 0) ? rr.x : (q == 1) ? rr.y : (q == 2) ? rr.z : rr.w;
                int fl = rec >> 26;
                int pos = lbase[fl] + atomicAdd(&ofs[fl], 1);
                if (pos < CAP2)
                    bins2[(size_t)(sb * 16 + fl) * CAP2 + pos] =
                        (rec & SMASK) | (((rec >> 18) & 255u) << 18);
            }
        }
    }
}

// ---------- fused degree + dinv + dx (per fine bucket) ----------
// bins2 stream is non-temporal: evict-first, keeps L2 clean for gather arrays.
__global__ void k_degdx(const unsigned* __restrict__ bins, const int* __restrict__ cursor,
                        const float* __restrict__ x,
                        float* __restrict__ dinv, float* __restrict__ dx, int N) {
    __shared__ int cnt[BSZ];
    int t = threadIdx.x, b = blockIdx.x;
    cnt[t] = 0;
    __syncthreads();
    int m = cursor[b * 16];
    if (m > CAP2) m = CAP2;
    int s = b * CAP2, e = s + m;
    int full = ((e - s) >> 10) << 10;
    int ev = s + full;
    for (int j = s + (t << 2); j < ev; j += 1024) {
        uint4e rr = __builtin_nontemporal_load(reinterpret_cast<const uint4e*>(bins + j));
        atomicAdd(&cnt[rr[0] >> 18], 1);
        atomicAdd(&cnt[rr[1] >> 18], 1);
        atomicAdd(&cnt[rr[2] >> 18], 1);
        atomicAdd(&cnt[rr[3] >> 18], 1);
    }
    for (int j = ev + t; j < e; j += 256)
        atomicAdd(&cnt[__builtin_nontemporal_load(bins + j) >> 18], 1);
    __syncthreads();
    int node = (b << BSH) + t;
    if (node < N) {
        float d = rsqrtf((float)(cnt[t] + 1));
        dinv[node] = d;
        dx[node] = d * x[node];
    }
}

// ---------- layer-1 scalar aggregate (per fine bucket) ----------
// bins2 stream non-temporal so the dx gather array (1 MB) stays L2-resident.
__global__ void k_s1(const unsigned* __restrict__ bins, const int* __restrict__ cursor,
                     const float* __restrict__ dinv, const float* __restrict__ dx,
                     const float* __restrict__ ts,
                     float2* __restrict__ gpq, int N) {
    __shared__ float sacc[BSZ];
    int t = threadIdx.x, b = blockIdx.x;
    sacc[t] = 0.0f;
    __syncthreads();
    int m = cursor[b * 16];
    if (m > CAP2) m = CAP2;
    int s = b * CAP2, e = s + m;
    int full = ((e - s) >> 10) << 10;
    int ev = s + full;
    for (int j = s + (t << 2); j < ev; j += 1024) {
        uint4e rr = __builtin_nontemporal_load(reinterpret_cast<const uint4e*>(bins + j));
        float v0 = dx[rr[0] & SMASK], v1 = dx[rr[1] & SMASK],
              v2 = dx[rr[2] & SMASK], v3 = dx[rr[3] & SMASK];
        atomicAdd(&sacc[rr[0] >> 18], v0);
        atomicAdd(&sacc[rr[1] >> 18], v1);
        atomicAdd(&sacc[rr[2] >> 18], v2);
        atomicAdd(&sacc[rr[3] >> 18], v3);
    }
    for (int j = ev + t; j < e; j += 256) {
        unsigned r = __builtin_nontemporal_load(bins + j);
        atomicAdd(&sacc[r >> 18], dx[r & SMASK]);
    }
    __syncthreads();
    int node = (b << BSH) + t;
    if (node < N) {
        float d = dinv[node];
        float S = d * (sacc[t] + dx[node]);   // + self-loop dinv^2*x
        int k = 0;
        #pragma unroll
        for (int g = 0; g < HD; ++g) k += (S > ts[g]);
        unsigned dq = (__float_as_uint(d) & ~31u) | (unsigned)k;
        gpq[node] = make_float2(d * S, __uint_as_float(dq));
    }
}

// ---------- layer-2: interval-bucketed LDS aggregate + fused recon/epilogue ----------
// R11 champion form: two scalar ds_add_f32 per edge (no packed f32 LDS atomic
// exists on gfx950), NT stream loads, NT output store.
__global__ void __launch_bounds__(AGT, 1)
k_agg(const unsigned* __restrict__ bins, const int* __restrict__ cursor,
      const float2* __restrict__ gpq, const float* __restrict__ dinv,
      const int* __restrict__ splits, const int* __restrict__ signs,
      const float* __restrict__ W1, const float* __restrict__ b1,
      const float* __restrict__ W2, const float* __restrict__ b2,
      const float* __restrict__ Wfc, const float* __restrict__ bfc,
      float* __restrict__ out, int N) {
    __shared__ float acc[BSZ * STR];   // 35.8 KB
    int t = threadIdx.x, b = blockIdx.x;
    for (int i = t; i < BSZ * STR; i += AGT) acc[i] = 0.0f;
    __syncthreads();

    int m = cursor[b * 16];
    if (m > CAP2) m = CAP2;
    int s = b * CAP2, e = s + m;
    int nv = m >> 2;                       // full uint4 groups (s is 16B-aligned)
    const uint4e* b4 = reinterpret_cast<const uint4e*>(bins + s);
    for (int i = t; i < nv; i += AGT) {
        uint4e rr = __builtin_nontemporal_load(b4 + i);
        float2 p0 = gpq[rr[0] & SMASK], p1 = gpq[rr[1] & SMASK],
               p2 = gpq[rr[2] & SMASK], p3 = gpq[rr[3] & SMASK];
        float* a0 = &acc[(int)(rr[0] >> 18) * STR + 2 * (int)(__float_as_uint(p0.y) & 31u)];
        float* a1 = &acc[(int)(rr[1] >> 18) * STR + 2 * (int)(__float_as_uint(p1.y) & 31u)];
        float* a2 = &acc[(int)(rr[2] >> 18) * STR + 2 * (int)(__float_as_uint(p2.y) & 31u)];
        float* a3 = &acc[(int)(rr[3] >> 18) * STR + 2 * (int)(__float_as_uint(p3.y) & 31u)];
        atomicAdd(a0, p0.x); atomicAdd(a0 + 1, p0.y);
        atomicAdd(a1, p1.x); atomicAdd(a1 + 1, p1.y);
        atomicAdd(a2, p2.x); atomicAdd(a2 + 1, p2.y);
        atomicAdd(a3, p3.x); atomicAdd(a3 + 1, p3.y);
    }
    for (int j = s + (nv << 2) + t; j < e; j += AGT) {
        unsigned r = __builtin_nontemporal_load(bins + j);
        float2 p = gpq[r & SMASK];
        float* a = &acc[(int)(r >> 18) * STR + 2 * (int)(__float_as_uint(p.y) & 31u)];
        atomicAdd(a, p.x); atomicAdd(a + 1, p.y);
    }
    __syncthreads();

    // ---- reconstruction + epilogue (first 256 lanes; one node each) ----
    int node = (b << BSH) + t;
    if (t >= BSZ || node >= N) return;
    float Ppre[NIV + 1], Qpre[NIV + 1];
    float pp = 0.0f, qq = 0.0f;
    #pragma unroll
    for (int mm = 0; mm < NIV; ++mm) {
        Ppre[mm] = pp; Qpre[mm] = qq;
        pp += acc[t * STR + 2 * mm];
        qq += acc[t * STR + 2 * mm + 1];
    }
    Ppre[NIV] = pp; Qpre[NIV] = qq;

    float2 pq = gpq[node];
    float di = dinv[node];        // exact dinv (gpq.y carries packed k bits)
    float si = pq.x / di;         // S = (d*S)/d
    float aggv[HD];
    #pragma unroll
    for (int f = 0; f < HD; ++f) {
        int sp = splits[f], sg = signs[f];
        float w = W1[f], bb = b1[f];
        float A, B;
        if (sg > 0)      { A = pp - Ppre[sp]; B = qq - Qpre[sp]; }
        else if (sg < 0) { A = Ppre[sp];      B = Qpre[sp]; }
        else             { A = 0.0f;          B = (bb > 0.0f) ? qq : 0.0f; }
        float selfh = fmaxf(fmaf(w, si, bb), 0.0f);
        aggv[f] = di * (fmaf(w, A, bb * B) + di * selfh);
    }
    float o0 = bfc[0], o1 = bfc[1], o2 = bfc[2], o3 = bfc[3];
    #pragma unroll
    for (int f2 = 0; f2 < HD; ++f2) {
        float h = b2[f2];
        #pragma unroll
        for (int k = 0; k < HD; ++k) h = fmaf(aggv[k], W2[k * HD + f2], h);
        h = fmaxf(h, 0.0f);
        o0 = fmaf(h, Wfc[f2 * NC + 0], o0);
        o1 = fmaf(h, Wfc[f2 * NC + 1], o1);
        o2 = fmaf(h, Wfc[f2 * NC + 2], o2);
        o3 = fmaf(h, Wfc[f2 * NC + 3], o3);
    }
    float4e ov = { o0, o1, o2, o3 };
    __builtin_nontemporal_store(ov, reinterpret_cast<float4e*>(out) + node);
}

extern "C" void kernel_launch(void* const* d_in, const int* in_sizes, int n_in,
                              void* d_out, int out_size, void* d_ws, size_t ws_size,
                              hipStream_t stream) {
    const float* x   = (const float*)d_in[0];
    const int*   ei  = (const int*)d_in[1];
    const float* W1  = (const float*)d_in[2];
    const float* b1  = (const float*)d_in[3];
    const float* W2  = (const float*)d_in[4];
    const float* b2  = (const float*)d_in[5];
    const float* Wfc = (const float*)d_in[6];
    const float* bfc = (const float*)d_in[7];
    float* out = (float*)d_out;

    const int N = in_sizes[0];            // 250000 (< 2^18)
    const int E = in_sizes[1] / 2;        // 4000000
    const int* row = ei;
    const int* col = ei + E;

    // workspace layout (~59 MB)
    char* ws = (char*)d_ws;
    size_t off = 0;
    unsigned* bins1 = (unsigned*)(ws + off); off += (size_t)NSB * NB1 * CAPB * 4; // 33.6 MB
    unsigned* bins2 = (unsigned*)(ws + off); off += (size_t)NFB * CAP2 * 4;       // 21 MB
    int*    cnts1 = (int*)(ws + off);    off += (size_t)NSB * NB1 * 4;            // 256 KB
    int*    cursor2= (int*)(ws + off);   off += (size_t)NFB * 16 * 4;             // 64 KB (zeroed in k_thr)
    float*  dinv  = (float*)(ws + off);  off += (size_t)N * 4;
    float*  dx    = (float*)(ws + off);  off += (size_t)N * 4;
    float2* gpq   = (float2*)(ws + off); off += (size_t)N * 8;                    // (d*S, d|k)
    float*  ts    = (float*)(ws + off);  off += 64;
    int*    splits= (int*)(ws + off);    off += 64;
    int*    signs = (int*)(ws + off);    off += 64;

    const int B = 256;
    k_thr<<<1, B, 0, stream>>>(W1, b1, ts, splits, signs,
                               cursor2, NFB * 16);
    int CHK = (E + NB1 - 1) / NB1;
    CHK = (CHK + 3) & ~3;                 // 4-aligned chunks (CHK=3908)
    k_part1<<<NB1, B, 0, stream>>>(row, col, cnts1, bins1, E, CHK);
    k_part2<<<NSB * 16, B, 0, stream>>>(bins1, cnts1, cursor2, bins2);
    k_degdx<<<NFB, B, 0, stream>>>(bins2, cursor2, x, dinv, dx, N);
    k_s1<<<NFB, B, 0, stream>>>(bins2, cursor2, dinv, dx, ts, gpq, N);
    k_agg<<<NFB, AGT, 0, stream>>>(bins2, cursor2, gpq, dinv, splits, signs,
                                   W1, b1, W2, b2, Wfc, bfc, out, N);
}

// Round 14
// 209.232 us; speedup vs baseline: 1.2671x; 1.0019x over previous
//
#include <hip/hip_runtime.h>
#include <math.h>

#define HD 16      // hidden dim
#define NC 4       // num classes
#define BSH 8      // log2(nodes per fine bucket)
#define BSZ 256    // nodes per fine bucket
#define NSB 64     // super-buckets (64 * 4096 = 262144 >= N)
#define SBSH 12    // log2(nodes per super-bucket)
#define NB1 1024   // part1 blocks (fixed: region index uses 10 bits)
#define CAPB 128   // per-(block,sb) region capacity (lambda=61; P(ovf)~5e-8; pow2 -> shifts)
#define CAP2S 384  // per-(fine-bucket, slice) segment capacity (lambda=256, +8sigma)
#define NFB 1024   // fine buckets total (NSB * 16)
#define NIV 17     // intervals = HD + 1
#define STR 35     // LDS P/Q row stride per node (odd -> conflict-free)
#define AGT 512    // k_agg threads (4 blocks/CU x 512 = 2048 = 100% thread slots)
#define SMASK 0x3FFFFu  // low 18 bits = src id

// ext_vector types: __builtin_nontemporal_* accepts these (not HIP_vector_type)
typedef unsigned uint4e __attribute__((ext_vector_type(4)));
typedef float    float4e __attribute__((ext_vector_type(4)));

// ---------- prep: sorted relu thresholds + per-feature split/sign ----------
// (no cursor zeroing needed anymore: cnts1/cnts2 are fully written each run)
__global__ void k_thr(const float* __restrict__ W1, const float* __restrict__ b1,
                      float* __restrict__ ts, int* __restrict__ splits,
                      int* __restrict__ signs) {
    if (threadIdx.x != 0 || blockIdx.x != 0) return;
    float tt[HD], s[HD];
    for (int f = 0; f < HD; ++f) {
        float w = W1[f];
        tt[f] = (w != 0.0f) ? (-b1[f] / w) : INFINITY;
        s[f] = tt[f];
    }
    for (int i = 1; i < HD; ++i) {            // insertion sort
        float key = s[i]; int j = i - 1;
        while (j >= 0 && s[j] > key) { s[j + 1] = s[j]; --j; }
        s[j + 1] = key;
    }
    for (int f = 0; f < HD; ++f) ts[f] = s[f];
    for (int f = 0; f < HD; ++f) {
        float w = W1[f];
        if (w == 0.0f) { signs[f] = 0; splits[f] = 0; continue; }
        int c = 0;
        for (int g = 0; g < HD; ++g) c += (s[g] < tt[f]) ? 1 : 0;
        splits[f] = c + 1;                    // prefix index
        signs[f] = (w > 0.0f) ? 1 : -1;
    }
}

// ---------- pass 1 (single-phase): partition edges into 64 super-buckets ----------
// Fixed exclusive regions bins1[sb][b][CAPB]; one LDS atomic per edge (R13 win).
__global__ void k_part1(const int* __restrict__ row, const int* __restrict__ col,
                        int* __restrict__ cnts1, unsigned* __restrict__ bins1,
                        int E, int CHK) {
    __shared__ int ofs[NSB];
    int t = threadIdx.x;
    int b = blockIdx.x;
    int cb = b * CHK;
    int ce = min(E, cb + CHK);
    int n = ce - cb; if (n < 0) n = 0;
    if (t < NSB) ofs[t] = 0;
    __syncthreads();
    int nv = n >> 2;                       // uint4 groups (cb is 4-aligned)
    const uint4* col4 = reinterpret_cast<const uint4*>(col + cb);
    const uint4* row4 = reinterpret_cast<const uint4*>(row + cb);
    for (int i = t; i < nv; i += 256) {
        uint4 c4 = col4[i];
        uint4 r4 = row4[i];
        {
            unsigned c = c4.x; int sb = (int)(c >> SBSH);
            int pos = atomicAdd(&ofs[sb], 1);
            if (pos < CAPB)
                bins1[((((size_t)sb << 10) | b) << 7) + pos] = r4.x | ((c & 4095u) << 18);
        }
        {
            unsigned c = c4.y; int sb = (int)(c >> SBSH);
            int pos = atomicAdd(&ofs[sb], 1);
            if (pos < CAPB)
                bins1[((((size_t)sb << 10) | b) << 7) + pos] = r4.y | ((c & 4095u) << 18);
        }
        {
            unsigned c = c4.z; int sb = (int)(c >> SBSH);
            int pos = atomicAdd(&ofs[sb], 1);
            if (pos < CAPB)
                bins1[((((size_t)sb << 10) | b) << 7) + pos] = r4.z | ((c & 4095u) << 18);
        }
        {
            unsigned c = c4.w; int sb = (int)(c >> SBSH);
            int pos = atomicAdd(&ofs[sb], 1);
            if (pos < CAPB)
                bins1[((((size_t)sb << 10) | b) << 7) + pos] = r4.w | ((c & 4095u) << 18);
        }
    }
    for (int e = (nv << 2) + t; e < n; e += 256) {
        unsigned c = (unsigned)col[cb + e];
        int sb = (int)(c >> SBSH);
        int pos = atomicAdd(&ofs[sb], 1);
        if (pos < CAPB)
            bins1[((((size_t)sb << 10) | b) << 7) + pos] =
                (unsigned)row[cb + e] | ((c & 4095u) << 18);
    }
    __syncthreads();
    if (t < NSB) cnts1[t * NB1 + b] = ofs[t];   // layout cnts1[sb][b]
}

// ---------- pass 2 (single-phase): split super-bucket slices into fixed segments ----------
// R14: each (fine-bucket fl, slice sp) owns segment bins2[fb][sp][CAP2S].
// One LDS ofs atomic per record; NO hist phase, NO second bins1 scan,
// NO global cursor atomics. Exact counts written to cnts2[fb*16+sp].
__global__ void k_part2(const unsigned* __restrict__ bins1, const int* __restrict__ cnts1,
                        int* __restrict__ cnts2, unsigned* __restrict__ bins2) {
    __shared__ int ofs[16];
    __shared__ int cnt[64];
    int t = threadIdx.x;
    int sb = blockIdx.x >> 4;
    int sp = blockIdx.x & 15;
    if (t < 64) {
        int c = cnts1[sb * NB1 + sp * 64 + t];
        cnt[t] = (c > CAPB) ? CAPB : c;
    }
    if (t < 16) ofs[t] = 0;
    __syncthreads();
    const unsigned* base = bins1 + ((((size_t)sb << 10) | (sp * 64)) << 7);
    for (int j = t << 2; j < 64 * CAPB; j += 1024) {
        uint4 rr = *reinterpret_cast<const uint4*>(base + j);
        int cs = cnt[j >> 7];
        int p0 = j & 127;
        #pragma unroll
        for (int q = 0; q < 4; ++q) {
            if (p0 + q < cs) {
                unsigned rec = (q == 0) ? rr.x : (q == 1) ? rr.y : (q == 2) ? rr.z : rr.w;
                int fl = rec >> 26;
                int pos = atomicAdd(&ofs[fl], 1);
                if (pos < CAP2S)
                    bins2[((size_t)(sb * 16 + fl) * 16 + sp) * CAP2S + pos] =
                        (rec & SMASK) | (((rec >> 18) & 255u) << 18);
            }
        }
    }
    __syncthreads();
    if (t < 16) {
        int c = ofs[t];
        cnts2[(sb * 16 + t) * 16 + sp] = (c > CAP2S) ? CAP2S : c;
    }
}

// ---------- fused degree + dinv + dx (per fine bucket; 16 ragged segments) ----------
__global__ void k_degdx(const unsigned* __restrict__ bins, const int* __restrict__ cnts2,
                        const float* __restrict__ x,
                        float* __restrict__ dinv, float* __restrict__ dx, int N) {
    __shared__ int cnt[BSZ];
    __shared__ int cs_[16];
    __shared__ int gb[17];
    int t = threadIdx.x, b = blockIdx.x;
    cnt[t] = 0;
    if (t < 16) {
        int c = cnts2[b * 16 + t];
        cs_[t] = (c > CAP2S) ? CAP2S : c;
    }
    __syncthreads();
    if (t == 0) {
        int a = 0;
        for (int s2 = 0; s2 < 16; ++s2) { gb[s2] = a; a += (cs_[s2] + 3) >> 2; }
        gb[16] = a;
    }
    __syncthreads();
    int gtot = gb[16];
    const unsigned* bb = bins + (size_t)b * 16 * CAP2S;
    for (int g = t; g < gtot; g += 256) {
        int seg = 0;
        #pragma unroll
        for (int s2 = 1; s2 < 16; ++s2) seg += (g >= gb[s2]);   // broadcast LDS reads
        int pos = (g - gb[seg]) << 2;
        int cs = cs_[seg];
        uint4e rr = __builtin_nontemporal_load(
            reinterpret_cast<const uint4e*>(bb + seg * CAP2S + pos));
        if (pos + 0 < cs) atomicAdd(&cnt[rr[0] >> 18], 1);
        if (pos + 1 < cs) atomicAdd(&cnt[rr[1] >> 18], 1);
        if (pos + 2 < cs) atomicAdd(&cnt[rr[2] >> 18], 1);
        if (pos + 3 < cs) atomicAdd(&cnt[rr[3] >> 18], 1);
    }
    __syncthreads();
    int node = (b << BSH) + t;
    if (node < N) {
        float d = rsqrtf((float)(cnt[t] + 1));
        dinv[node] = d;
        dx[node] = d * x[node];
    }
}

// ---------- layer-1 scalar aggregate (per fine bucket; 16 ragged segments) ----------
__global__ void k_s1(const unsigned* __restrict__ bins, const int* __restrict__ cnts2,
                     const float* __restrict__ dinv, const float* __restrict__ dx,
                     const float* __restrict__ ts,
                     float2* __restrict__ gpq, int N) {
    __shared__ float sacc[BSZ];
    __shared__ int cs_[16];
    __shared__ int gb[17];
    int t = threadIdx.x, b = blockIdx.x;
    sacc[t] = 0.0f;
    if (t < 16) {
        int c = cnts2[b * 16 + t];
        cs_[t] = (c > CAP2S) ? CAP2S : c;
    }
    __syncthreads();
    if (t == 0) {
        int a = 0;
        for (int s2 = 0; s2 < 16; ++s2) { gb[s2] = a; a += (cs_[s2] + 3) >> 2; }
        gb[16] = a;
    }
    __syncthreads();
    int gtot = gb[16];
    const unsigned* bb = bins + (size_t)b * 16 * CAP2S;
    for (int g = t; g < gtot; g += 256) {
        int seg = 0;
        #pragma unroll
        for (int s2 = 1; s2 < 16; ++s2) seg += (g >= gb[s2]);
        int pos = (g - gb[seg]) << 2;
        int cs = cs_[seg];
        uint4e rr = __builtin_nontemporal_load(
            reinterpret_cast<const uint4e*>(bb + seg * CAP2S + pos));
        if (pos + 0 < cs) atomicAdd(&sacc[rr[0] >> 18], dx[rr[0] & SMASK]);
        if (pos + 1 < cs) atomicAdd(&sacc[rr[1] >> 18], dx[rr[1] & SMASK]);
        if (pos + 2 < cs) atomicAdd(&sacc[rr[2] >> 18], dx[rr[2] & SMASK]);
        if (pos + 3 < cs) atomicAdd(&sacc[rr[3] >> 18], dx[rr[3] & SMASK]);
    }
    __syncthreads();
    int node = (b << BSH) + t;
    if (node < N) {
        float d = dinv[node];
        float S = d * (sacc[t] + dx[node]);   // + self-loop dinv^2*x
        int k = 0;
        #pragma unroll
        for (int g = 0; g < HD; ++g) k += (S > ts[g]);
        unsigned dq = (__float_as_uint(d) & ~31u) | (unsigned)k;
        gpq[node] = make_float2(d * S, __uint_as_float(dq));
    }
}

// ---------- layer-2: interval-bucketed LDS aggregate + fused recon/epilogue ----------
__global__ void __launch_bounds__(AGT, 1)
k_agg(const unsigned* __restrict__ bins, const int* __restrict__ cnts2,
      const float2* __restrict__ gpq, const float* __restrict__ dinv,
      const int* __restrict__ splits, const int* __restrict__ signs,
      const float* __restrict__ W1, const float* __restrict__ b1,
      const float* __restrict__ W2, const float* __restrict__ b2,
      const float* __restrict__ Wfc, const float* __restrict__ bfc,
      float* __restrict__ out, int N) {
    __shared__ float acc[BSZ * STR];   // 35.8 KB
    __shared__ int cs_[16];
    __shared__ int gb[17];
    int t = threadIdx.x, b = blockIdx.x;
    for (int i = t; i < BSZ * STR; i += AGT) acc[i] = 0.0f;
    if (t < 16) {
        int c = cnts2[b * 16 + t];
        cs_[t] = (c > CAP2S) ? CAP2S : c;
    }
    __syncthreads();
    if (t == 0) {
        int a = 0;
        for (int s2 = 0; s2 < 16; ++s2) { gb[s2] = a; a += (cs_[s2] + 3) >> 2; }
        gb[16] = a;
    }
    __syncthreads();
    int gtot = gb[16];
    const unsigned* bb = bins + (size_t)b * 16 * CAP2S;
    for (int g = t; g < gtot; g += AGT) {
        int seg = 0;
        #pragma unroll
        for (int s2 = 1; s2 < 16; ++s2) seg += (g >= gb[s2]);
        int pos = (g - gb[seg]) << 2;
        int cs = cs_[seg];
        uint4e rr = __builtin_nontemporal_load(
            reinterpret_cast<const uint4e*>(bb + seg * CAP2S + pos));
        if (pos + 0 < cs) {
            float2 p = gpq[rr[0] & SMASK];
            float* a = &acc[(int)(rr[0] >> 18) * STR + 2 * (int)(__float_as_uint(p.y) & 31u)];
            atomicAdd(a, p.x); atomicAdd(a + 1, p.y);
        }
        if (pos + 1 < cs) {
            float2 p = gpq[rr[1] & SMASK];
            float* a = &acc[(int)(rr[1] >> 18) * STR + 2 * (int)(__float_as_uint(p.y) & 31u)];
            atomicAdd(a, p.x); atomicAdd(a + 1, p.y);
        }
        if (pos + 2 < cs) {
            float2 p = gpq[rr[2] & SMASK];
            float* a = &acc[(int)(rr[2] >> 18) * STR + 2 * (int)(__float_as_uint(p.y) & 31u)];
            atomicAdd(a, p.x); atomicAdd(a + 1, p.y);
        }
        if (pos + 3 < cs) {
            float2 p = gpq[rr[3] & SMASK];
            float* a = &acc[(int)(rr[3] >> 18) * STR + 2 * (int)(__float_as_uint(p.y) & 31u)];
            atomicAdd(a, p.x); atomicAdd(a + 1, p.y);
        }
    }
    __syncthreads();

    // ---- reconstruction + epilogue (first 256 lanes; one node each) ----
    int node = (b << BSH) + t;
    if (t >= BSZ || node >= N) return;
    float Ppre[NIV + 1], Qpre[NIV + 1];
    float pp = 0.0f, qq = 0.0f;
    #pragma unroll
    for (int mm = 0; mm < NIV; ++mm) {
        Ppre[mm] = pp; Qpre[mm] = qq;
        pp += acc[t * STR + 2 * mm];
        qq += acc[t * STR + 2 * mm + 1];
    }
    Ppre[NIV] = pp; Qpre[NIV] = qq;

    float2 pq = gpq[node];
    float di = dinv[node];        // exact dinv (gpq.y carries packed k bits)
    float si = pq.x / di;         // S = (d*S)/d
    float aggv[HD];
    #pragma unroll
    for (int f = 0; f < HD; ++f) {
        int sp = splits[f], sg = signs[f];
        float w = W1[f], bb2 = b1[f];
        float A, B;
        if (sg > 0)      { A = pp - Ppre[sp]; B = qq - Qpre[sp]; }
        else if (sg < 0) { A = Ppre[sp];      B = Qpre[sp]; }
        else             { A = 0.0f;          B = (bb2 > 0.0f) ? qq : 0.0f; }
        float selfh = fmaxf(fmaf(w, si, bb2), 0.0f);
        aggv[f] = di * (fmaf(w, A, bb2 * B) + di * selfh);
    }
    float o0 = bfc[0], o1 = bfc[1], o2 = bfc[2], o3 = bfc[3];
    #pragma unroll
    for (int f2 = 0; f2 < HD; ++f2) {
        float h = b2[f2];
        #pragma unroll
        for (int k = 0; k < HD; ++k) h = fmaf(aggv[k], W2[k * HD + f2], h);
        h = fmaxf(h, 0.0f);
        o0 = fmaf(h, Wfc[f2 * NC + 0], o0);
        o1 = fmaf(h, Wfc[f2 * NC + 1], o1);
        o2 = fmaf(h, Wfc[f2 * NC + 2], o2);
        o3 = fmaf(h, Wfc[f2 * NC + 3], o3);
    }
    float4e ov = { o0, o1, o2, o3 };
    __builtin_nontemporal_store(ov, reinterpret_cast<float4e*>(out) + node);
}

extern "C" void kernel_launch(void* const* d_in, const int* in_sizes, int n_in,
                              void* d_out, int out_size, void* d_ws, size_t ws_size,
                              hipStream_t stream) {
    const float* x   = (const float*)d_in[0];
    const int*   ei  = (const int*)d_in[1];
    const float* W1  = (const float*)d_in[2];
    const float* b1  = (const float*)d_in[3];
    const float* W2  = (const float*)d_in[4];
    const float* b2  = (const float*)d_in[5];
    const float* Wfc = (const float*)d_in[6];
    const float* bfc = (const float*)d_in[7];
    float* out = (float*)d_out;

    const int N = in_sizes[0];            // 250000 (< 2^18)
    const int E = in_sizes[1] / 2;        // 4000000
    const int* row = ei;
    const int* col = ei + E;

    // workspace layout (~63 MB)
    char* ws = (char*)d_ws;
    size_t off = 0;
    unsigned* bins1 = (unsigned*)(ws + off); off += (size_t)NSB * NB1 * CAPB * 4;   // 33.6 MB
    unsigned* bins2 = (unsigned*)(ws + off); off += (size_t)NFB * 16 * CAP2S * 4;   // 25.2 MB
    int*    cnts1 = (int*)(ws + off);    off += (size_t)NSB * NB1 * 4;              // 256 KB
    int*    cnts2 = (int*)(ws + off);    off += (size_t)NFB * 16 * 4;               // 64 KB
    float*  dinv  = (float*)(ws + off);  off += (size_t)N * 4;
    float*  dx    = (float*)(ws + off);  off += (size_t)N * 4;
    float2* gpq   = (float2*)(ws + off); off += (size_t)N * 8;                      // (d*S, d|k)
    float*  ts    = (float*)(ws + off);  off += 64;
    int*    splits= (int*)(ws + off);    off += 64;
    int*    signs = (int*)(ws + off);    off += 64;

    const int B = 256;
    k_thr<<<1, 64, 0, stream>>>(W1, b1, ts, splits, signs);
    int CHK = (E + NB1 - 1) / NB1;
    CHK = (CHK + 3) & ~3;                 // 4-aligned chunks (CHK=3908)
    k_part1<<<NB1, B, 0, stream>>>(row, col, cnts1, bins1, E, CHK);
    k_part2<<<NSB * 16, B, 0, stream>>>(bins1, cnts1, cnts2, bins2);
    k_degdx<<<NFB, B, 0, stream>>>(bins2, cnts2, x, dinv, dx, N);
    k_s1<<<NFB, B, 0, stream>>>(bins2, cnts2, dinv, dx, ts, gpq, N);
    k_agg<<<NFB, AGT, 0, stream>>>(bins2, cnts2, gpq, dinv, splits, signs,
                                   W1, b1, W2, b2, Wfc, bfc, out, N);
}

// Round 15
// 191.237 us; speedup vs baseline: 1.3863x; 1.0941x over previous
//
#include <hip/hip_runtime.h>
#include <math.h>

#define HD 16      // hidden dim
#define NC 4       // num classes
#define BSH 8      // log2(nodes per fine bucket)
#define BSZ 256    // nodes per fine bucket
#define NSB 64     // super-buckets (64 * 4096 = 262144 >= N)
#define SBSH 12    // log2(nodes per super-bucket)
#define NB1 1024   // part1 blocks (fixed: region index uses 10 bits)
#define CAPB 128   // per-(block,sb) region capacity (lambda=61; P(ovf)~5e-8; pow2 -> shifts)
#define CAP2S 384  // per-(fine-bucket, slice) segment capacity (lambda=256, +8sigma)
#define NFB 1024   // fine buckets total (NSB * 16)
#define NIV 17     // intervals = HD + 1
#define AGT 512    // k_agg threads (4 blocks/CU x 512 = 2048 = 100% thread slots)
#define FPS2 524288.0f       // 2^19 fixed-point scale
#define IFPS2 (1.0f/524288.0f)
#define CBIAS 16.0f          // positivity bias: uP encodes d*S + 16*d >= 0
#define SMASK 0x3FFFFu  // low 18 bits = src id

// ext_vector types: __builtin_nontemporal_* accepts these (not HIP_vector_type)
typedef unsigned uint4e __attribute__((ext_vector_type(4)));
typedef float    float4e __attribute__((ext_vector_type(4)));

// ---------- prep: sorted relu thresholds + per-feature split/sign ----------
__global__ void k_thr(const float* __restrict__ W1, const float* __restrict__ b1,
                      float* __restrict__ ts, int* __restrict__ splits,
                      int* __restrict__ signs) {
    if (threadIdx.x != 0 || blockIdx.x != 0) return;
    float tt[HD], s[HD];
    for (int f = 0; f < HD; ++f) {
        float w = W1[f];
        tt[f] = (w != 0.0f) ? (-b1[f] / w) : INFINITY;
        s[f] = tt[f];
    }
    for (int i = 1; i < HD; ++i) {            // insertion sort
        float key = s[i]; int j = i - 1;
        while (j >= 0 && s[j] > key) { s[j + 1] = s[j]; --j; }
        s[j + 1] = key;
    }
    for (int f = 0; f < HD; ++f) ts[f] = s[f];
    for (int f = 0; f < HD; ++f) {
        float w = W1[f];
        if (w == 0.0f) { signs[f] = 0; splits[f] = 0; continue; }
        int c = 0;
        for (int g = 0; g < HD; ++g) c += (s[g] < tt[f]) ? 1 : 0;
        splits[f] = c + 1;                    // prefix index
        signs[f] = (w > 0.0f) ? 1 : -1;
    }
}

// ---------- pass 1 (single-phase): partition edges into 64 super-buckets ----------
__global__ void k_part1(const int* __restrict__ row, const int* __restrict__ col,
                        int* __restrict__ cnts1, unsigned* __restrict__ bins1,
                        int E, int CHK) {
    __shared__ int ofs[NSB];
    int t = threadIdx.x;
    int b = blockIdx.x;
    int cb = b * CHK;
    int ce = min(E, cb + CHK);
    int n = ce - cb; if (n < 0) n = 0;
    if (t < NSB) ofs[t] = 0;
    __syncthreads();
    int nv = n >> 2;                       // uint4 groups (cb is 4-aligned)
    const uint4* col4 = reinterpret_cast<const uint4*>(col + cb);
    const uint4* row4 = reinterpret_cast<const uint4*>(row + cb);
    for (int i = t; i < nv; i += 256) {
        uint4 c4 = col4[i];
        uint4 r4 = row4[i];
        {
            unsigned c = c4.x; int sb = (int)(c >> SBSH);
            int pos = atomicAdd(&ofs[sb], 1);
            if (pos < CAPB)
                bins1[((((size_t)sb << 10) | b) << 7) + pos] = r4.x | ((c & 4095u) << 18);
        }
        {
            unsigned c = c4.y; int sb = (int)(c >> SBSH);
            int pos = atomicAdd(&ofs[sb], 1);
            if (pos < CAPB)
                bins1[((((size_t)sb << 10) | b) << 7) + pos] = r4.y | ((c & 4095u) << 18);
        }
        {
            unsigned c = c4.z; int sb = (int)(c >> SBSH);
            int pos = atomicAdd(&ofs[sb], 1);
            if (pos < CAPB)
                bins1[((((size_t)sb << 10) | b) << 7) + pos] = r4.z | ((c & 4095u) << 18);
        }
        {
            unsigned c = c4.w; int sb = (int)(c >> SBSH);
            int pos = atomicAdd(&ofs[sb], 1);
            if (pos < CAPB)
                bins1[((((size_t)sb << 10) | b) << 7) + pos] = r4.w | ((c & 4095u) << 18);
        }
    }
    for (int e = (nv << 2) + t; e < n; e += 256) {
        unsigned c = (unsigned)col[cb + e];
        int sb = (int)(c >> SBSH);
        int pos = atomicAdd(&ofs[sb], 1);
        if (pos < CAPB)
            bins1[((((size_t)sb << 10) | b) << 7) + pos] =
                (unsigned)row[cb + e] | ((c & 4095u) << 18);
    }
    __syncthreads();
    if (t < NSB) cnts1[t * NB1 + b] = ofs[t];   // layout cnts1[sb][b]
}

// ---------- pass 2 (single-phase): split super-bucket slices into fixed segments ----------
__global__ void k_part2(const unsigned* __restrict__ bins1, const int* __restrict__ cnts1,
                        int* __restrict__ cnts2, unsigned* __restrict__ bins2) {
    __shared__ int ofs[16];
    __shared__ int cnt[64];
    int t = threadIdx.x;
    int sb = blockIdx.x >> 4;
    int sp = blockIdx.x & 15;
    if (t < 64) {
        int c = cnts1[sb * NB1 + sp * 64 + t];
        cnt[t] = (c > CAPB) ? CAPB : c;
    }
    if (t < 16) ofs[t] = 0;
    __syncthreads();
    const unsigned* base = bins1 + ((((size_t)sb << 10) | (sp * 64)) << 7);
    for (int j = t << 2; j < 64 * CAPB; j += 1024) {
        uint4 rr = *reinterpret_cast<const uint4*>(base + j);
        int cs = cnt[j >> 7];
        int p0 = j & 127;
        #pragma unroll
        for (int q = 0; q < 4; ++q) {
            if (p0 + q < cs) {
                unsigned rec = (q == 0) ? rr.x : (q == 1) ? rr.y : (q == 2) ? rr.z : rr.w;
                int fl = rec >> 26;
                int pos = atomicAdd(&ofs[fl], 1);
                if (pos < CAP2S)
                    bins2[((size_t)(sb * 16 + fl) * 16 + sp) * CAP2S + pos] =
                        (rec & SMASK) | (((rec >> 18) & 255u) << 18);
            }
        }
    }
    __syncthreads();
    if (t < 16) {
        int c = ofs[t];
        cnts2[(sb * 16 + t) * 16 + sp] = (c > CAP2S) ? CAP2S : c;
    }
}

// ---------- fused degree + dinv + dx (per fine bucket; 16 ragged segments) ----------
__global__ void k_degdx(const unsigned* __restrict__ bins, const int* __restrict__ cnts2,
                        const float* __restrict__ x,
                        float* __restrict__ dinv, float* __restrict__ dx, int N) {
    __shared__ int cnt[BSZ];
    __shared__ int cs_[16];
    __shared__ int gb[17];
    int t = threadIdx.x, b = blockIdx.x;
    cnt[t] = 0;
    if (t < 16) {
        int c = cnts2[b * 16 + t];
        cs_[t] = (c > CAP2S) ? CAP2S : c;
    }
    __syncthreads();
    if (t == 0) {
        int a = 0;
        for (int s2 = 0; s2 < 16; ++s2) { gb[s2] = a; a += (cs_[s2] + 3) >> 2; }
        gb[16] = a;
    }
    __syncthreads();
    int gtot = gb[16];
    const unsigned* bb = bins + (size_t)b * 16 * CAP2S;
    for (int g = t; g < gtot; g += 256) {
        int seg = 0;
        #pragma unroll
        for (int s2 = 1; s2 < 16; ++s2) seg += (g >= gb[s2]);   // broadcast LDS reads
        int pos = (g - gb[seg]) << 2;
        int cs = cs_[seg];
        uint4e rr = __builtin_nontemporal_load(
            reinterpret_cast<const uint4e*>(bb + seg * CAP2S + pos));
        if (pos + 0 < cs) atomicAdd(&cnt[rr[0] >> 18], 1);
        if (pos + 1 < cs) atomicAdd(&cnt[rr[1] >> 18], 1);
        if (pos + 2 < cs) atomicAdd(&cnt[rr[2] >> 18], 1);
        if (pos + 3 < cs) atomicAdd(&cnt[rr[3] >> 18], 1);
    }
    __syncthreads();
    int node = (b << BSH) + t;
    if (node < N) {
        float d = rsqrtf((float)(cnt[t] + 1));
        dinv[node] = d;
        dx[node] = d * x[node];
    }
}

// ---------- layer-1 scalar aggregate (per fine bucket; 16 ragged segments) ----------
__global__ void k_s1(const unsigned* __restrict__ bins, const int* __restrict__ cnts2,
                     const float* __restrict__ dinv, const float* __restrict__ dx,
                     const float* __restrict__ ts,
                     float2* __restrict__ gpq, int N) {
    __shared__ float sacc[BSZ];
    __shared__ int cs_[16];
    __shared__ int gb[17];
    int t = threadIdx.x, b = blockIdx.x;
    sacc[t] = 0.0f;
    if (t < 16) {
        int c = cnts2[b * 16 + t];
        cs_[t] = (c > CAP2S) ? CAP2S : c;
    }
    __syncthreads();
    if (t == 0) {
        int a = 0;
        for (int s2 = 0; s2 < 16; ++s2) { gb[s2] = a; a += (cs_[s2] + 3) >> 2; }
        gb[16] = a;
    }
    __syncthreads();
    int gtot = gb[16];
    const unsigned* bb = bins + (size_t)b * 16 * CAP2S;
    for (int g = t; g < gtot; g += 256) {
        int seg = 0;
        #pragma unroll
        for (int s2 = 1; s2 < 16; ++s2) seg += (g >= gb[s2]);
        int pos = (g - gb[seg]) << 2;
        int cs = cs_[seg];
        uint4e rr = __builtin_nontemporal_load(
            reinterpret_cast<const uint4e*>(bb + seg * CAP2S + pos));
        if (pos + 0 < cs) atomicAdd(&sacc[rr[0] >> 18], dx[rr[0] & SMASK]);
        if (pos + 1 < cs) atomicAdd(&sacc[rr[1] >> 18], dx[rr[1] & SMASK]);
        if (pos + 2 < cs) atomicAdd(&sacc[rr[2] >> 18], dx[rr[2] & SMASK]);
        if (pos + 3 < cs) atomicAdd(&sacc[rr[3] >> 18], dx[rr[3] & SMASK]);
    }
    __syncthreads();
    int node = (b << BSH) + t;
    if (node < N) {
        float d = dinv[node];
        float S = d * (sacc[t] + dx[node]);   // + self-loop dinv^2*x
        int k = 0;
        #pragma unroll
        for (int g = 0; g < HD; ++g) k += (S > ts[g]);
        unsigned dq = (__float_as_uint(d) & ~31u) | (unsigned)k;
        gpq[node] = make_float2(d * S, __uint_as_float(dq));
    }
}

// ---------- layer-2: interval-bucketed LDS aggregate + fused recon/epilogue ----------
// R15: ONE u64 fixed-point LDS atomic per edge (was two f32 atomics).
// hi word = (d*S + 16*d) * 2^19 (bias keeps it >= 0); lo word = d * 2^19.
// lo sums < 2^26 -> no carry into hi; hi sums < deg*2^24 < 2^31 for deg<128.
// Epilogue: Q = lo*2^-19, P = hi*2^-19 - 16*Q. Added abs error ~3e-4
// (threshold 4.2e-3, current absmax 9.8e-4 -> ~4x headroom).
// This is the op-rate-vs-bank-cycle probe of the LDS atomic pipe.
__global__ void __launch_bounds__(AGT, 1)
k_agg(const unsigned* __restrict__ bins, const int* __restrict__ cnts2,
      const float2* __restrict__ gpq, const float* __restrict__ dinv,
      const int* __restrict__ splits, const int* __restrict__ signs,
      const float* __restrict__ W1, const float* __restrict__ b1,
      const float* __restrict__ W2, const float* __restrict__ b2,
      const float* __restrict__ Wfc, const float* __restrict__ bfc,
      float* __restrict__ out, int N) {
    __shared__ unsigned long long acc[BSZ * NIV];   // 34.8 KB; stride 17 (odd) u64
    __shared__ int cs_[16];
    __shared__ int gb[17];
    int t = threadIdx.x, b = blockIdx.x;
    for (int i = t; i < BSZ * NIV; i += AGT) acc[i] = 0ull;
    if (t < 16) {
        int c = cnts2[b * 16 + t];
        cs_[t] = (c > CAP2S) ? CAP2S : c;
    }
    __syncthreads();
    if (t == 0) {
        int a = 0;
        for (int s2 = 0; s2 < 16; ++s2) { gb[s2] = a; a += (cs_[s2] + 3) >> 2; }
        gb[16] = a;
    }
    __syncthreads();
    int gtot = gb[16];
    const unsigned* bb = bins + (size_t)b * 16 * CAP2S;
    for (int g = t; g < gtot; g += AGT) {
        int seg = 0;
        #pragma unroll
        for (int s2 = 1; s2 < 16; ++s2) seg += (g >= gb[s2]);
        int pos = (g - gb[seg]) << 2;
        int cs = cs_[seg];
        uint4e rr = __builtin_nontemporal_load(
            reinterpret_cast<const uint4e*>(bb + seg * CAP2S + pos));
        #pragma unroll
        for (int q = 0; q < 4; ++q) {
            if (pos + q < cs) {
                unsigned rec = rr[q];
                float2 p = gpq[rec & SMASK];
                int k = (int)(__float_as_uint(p.y) & 31u);
                float dq = p.y;                              // d (low bits carry k)
                float vP = fmaf(CBIAS, dq, p.x);             // d*S + 16*d >= 0
                unsigned uP = (unsigned)(vP * FPS2 + 0.5f);  // cvt clamps negatives to 0
                unsigned uQ = (unsigned)(dq * FPS2 + 0.5f);
                unsigned long long pk = ((unsigned long long)uP << 32) | (unsigned long long)uQ;
                atomicAdd(&acc[(int)(rec >> 18) * NIV + k], pk);
            }
        }
    }
    __syncthreads();

    // ---- reconstruction + epilogue (first 256 lanes; one node each) ----
    int node = (b << BSH) + t;
    if (t >= BSZ || node >= N) return;
    float Ppre[NIV + 1], Qpre[NIV + 1];
    float pp = 0.0f, qq = 0.0f;
    #pragma unroll
    for (int mm = 0; mm < NIV; ++mm) {
        Ppre[mm] = pp; Qpre[mm] = qq;
        unsigned long long v = acc[t * NIV + mm];
        float Q = (float)(unsigned)(v & 0xFFFFFFFFull) * IFPS2;
        float Ph = (float)(unsigned)(v >> 32) * IFPS2;
        pp += fmaf(-CBIAS, Q, Ph);          // P = Phat - 16*Q
        qq += Q;
    }
    Ppre[NIV] = pp; Qpre[NIV] = qq;

    float2 pq = gpq[node];
    float di = dinv[node];        // exact dinv (gpq.y carries packed k bits)
    float si = pq.x / di;         // S = (d*S)/d
    float aggv[HD];
    #pragma unroll
    for (int f = 0; f < HD; ++f) {
        int sp = splits[f], sg = signs[f];
        float w = W1[f], bb2 = b1[f];
        float A, B;
        if (sg > 0)      { A = pp - Ppre[sp]; B = qq - Qpre[sp]; }
        else if (sg < 0) { A = Ppre[sp];      B = Qpre[sp]; }
        else             { A = 0.0f;          B = (bb2 > 0.0f) ? qq : 0.0f; }
        float selfh = fmaxf(fmaf(w, si, bb2), 0.0f);
        aggv[f] = di * (fmaf(w, A, bb2 * B) + di * selfh);
    }
    float o0 = bfc[0], o1 = bfc[1], o2 = bfc[2], o3 = bfc[3];
    #pragma unroll
    for (int f2 = 0; f2 < HD; ++f2) {
        float h = b2[f2];
        #pragma unroll
        for (int k = 0; k < HD; ++k) h = fmaf(aggv[k], W2[k * HD + f2], h);
        h = fmaxf(h, 0.0f);
        o0 = fmaf(h, Wfc[f2 * NC + 0], o0);
        o1 = fmaf(h, Wfc[f2 * NC + 1], o1);
        o2 = fmaf(h, Wfc[f2 * NC + 2], o2);
        o3 = fmaf(h, Wfc[f2 * NC + 3], o3);
    }
    float4e ov = { o0, o1, o2, o3 };
    __builtin_nontemporal_store(ov, reinterpret_cast<float4e*>(out) + node);
}

extern "C" void kernel_launch(void* const* d_in, const int* in_sizes, int n_in,
                              void* d_out, int out_size, void* d_ws, size_t ws_size,
                              hipStream_t stream) {
    const float* x   = (const float*)d_in[0];
    const int*   ei  = (const int*)d_in[1];
    const float* W1  = (const float*)d_in[2];
    const float* b1  = (const float*)d_in[3];
    const float* W2  = (const float*)d_in[4];
    const float* b2  = (const float*)d_in[5];
    const float* Wfc = (const float*)d_in[6];
    const float* bfc = (const float*)d_in[7];
    float* out = (float*)d_out;

    const int N = in_sizes[0];            // 250000 (< 2^18)
    const int E = in_sizes[1] / 2;        // 4000000
    const int* row = ei;
    const int* col = ei + E;

    // workspace layout (~63 MB)
    char* ws = (char*)d_ws;
    size_t off = 0;
    unsigned* bins1 = (unsigned*)(ws + off); off += (size_t)NSB * NB1 * CAPB * 4;   // 33.6 MB
    unsigned* bins2 = (unsigned*)(ws + off); off += (size_t)NFB * 16 * CAP2S * 4;   // 25.2 MB
    int*    cnts1 = (int*)(ws + off);    off += (size_t)NSB * NB1 * 4;              // 256 KB
    int*    cnts2 = (int*)(ws + off);    off += (size_t)NFB * 16 * 4;               // 64 KB
    float*  dinv  = (float*)(ws + off);  off += (size_t)N * 4;
    float*  dx    = (float*)(ws + off);  off += (size_t)N * 4;
    float2* gpq   = (float2*)(ws + off); off += (size_t)N * 8;                      // (d*S, d|k)
    float*  ts    = (float*)(ws + off);  off += 64;
    int*    splits= (int*)(ws + off);    off += 64;
    int*    signs = (int*)(ws + off);    off += 64;

    const int B = 256;
    k_thr<<<1, 64, 0, stream>>>(W1, b1, ts, splits, signs);
    int CHK = (E + NB1 - 1) / NB1;
    CHK = (CHK + 3) & ~3;                 // 4-aligned chunks (CHK=3908)
    k_part1<<<NB1, B, 0, stream>>>(row, col, cnts1, bins1, E, CHK);
    k_part2<<<NSB * 16, B, 0, stream>>>(bins1, cnts1, cnts2, bins2);
    k_degdx<<<NFB, B, 0, stream>>>(bins2, cnts2, x, dinv, dx, N);
    k_s1<<<NFB, B, 0, stream>>>(bins2, cnts2, dinv, dx, ts, gpq, N);
    k_agg<<<NFB, AGT, 0, stream>>>(bins2, cnts2, gpq, dinv, splits, signs,
                                   W1, b1, W2, b2, Wfc, bfc, out, N);
}